// Round 1
// baseline (1374.736 us; speedup 1.0000x reference)
//
#include <hip/hip_runtime.h>
#include <float.h>

typedef unsigned long long u64;

#define NPTS 4096
#define CDIM 64
#define BATCH 8
#define KSEL 20

// workspace layout (float slots)
#define OFF_Y1 0
#define OFF_Y2 (BATCH * NPTS * 64)              // 2097152
#define OFF_SQ (2 * BATCH * NPTS * 64)          // 4194304
#define OFF_WT (OFF_SQ + BATCH * NPTS)          // 4227072
#define OFF_KNN (OFF_WT + 64 * 128)             // 4235264 (int area)

// ---------------------------------------------------------------------------
// k0: transform W (O=64 x 2C=128, row-major) into Wt[c][o'] (64 x 128):
//   o' <  64 : W1[o'][c]              = W[o'*128 + c]
//   o' >= 64 : (W2 - W1)[o'-64][c]    = W[(o'-64)*128 + 64 + c] - W[(o'-64)*128 + c]
// ---------------------------------------------------------------------------
__global__ void k0_wt(const float* __restrict__ W, float* __restrict__ Wt) {
    int f = blockIdx.x * 256 + threadIdx.x;
    if (f >= 64 * 128) return;
    int c = f >> 7, o = f & 127;
    float v;
    if (o < 64) {
        v = W[o * 128 + c];
    } else {
        int oo = o - 64;
        v = W[oo * 128 + 64 + c] - W[oo * 128 + c];
    }
    Wt[f] = v;
}

// ---------------------------------------------------------------------------
// k1: per 128-point tile: y1[n][o] = sum_c x[b][c][n] * Wt[c][o]   (o' 0..63)
//                         y2[n][o] = sum_c x[b][c][n] * Wt[c][64+o]
//                         sq[n]    = sum_c x[b][c][n]^2
// 256 blocks x 256 threads. 8x8 register blocking on a 128(n) x 128(o') tile.
// ---------------------------------------------------------------------------
__global__ __launch_bounds__(256) void k1_prep(const float* __restrict__ x,
                                               const float* __restrict__ Wtg,
                                               float* __restrict__ y1,
                                               float* __restrict__ y2,
                                               float* __restrict__ sq) {
    __shared__ float Xt[64][128];   // [c][n-local] — matches x layout
    __shared__ float Wt[64][128];   // [c][o']
    int tid = threadIdx.x;
    int gr0 = blockIdx.x * 128;           // global row (b*4096 + n)
    int b = gr0 >> 12;
    int n0 = gr0 & 4095;
    const float* xb = x + (size_t)b * (CDIM * NPTS) + n0;

    for (int k = 0; k < 32; k++) {
        int f = tid + 256 * k;
        int c = f >> 7, j = f & 127;
        Xt[c][j] = xb[c * NPTS + j];
        ((float*)Wt)[f] = Wtg[f];
    }
    __syncthreads();

    if (tid < 128) {
        float s = 0.f;
        for (int c = 0; c < 64; c++) { float v = Xt[c][tid]; s = fmaf(v, v, s); }
        sq[gr0 + tid] = s;
    }

    int tr = tid & 15, tc = tid >> 4;
    float acc[8][8];
#pragma unroll
    for (int i = 0; i < 8; i++)
#pragma unroll
        for (int j = 0; j < 8; j++) acc[i][j] = 0.f;

#pragma unroll 4
    for (int c = 0; c < 64; c++) {
        float a[8], bb[8];
        *(float4*)&a[0]  = *(const float4*)&Xt[c][8 * tr];
        *(float4*)&a[4]  = *(const float4*)&Xt[c][8 * tr + 4];
        *(float4*)&bb[0] = *(const float4*)&Wt[c][8 * tc];
        *(float4*)&bb[4] = *(const float4*)&Wt[c][8 * tc + 4];
#pragma unroll
        for (int i = 0; i < 8; i++)
#pragma unroll
            for (int j = 0; j < 8; j++) acc[i][j] = fmaf(a[i], bb[j], acc[i][j]);
    }

    // store: o' < 64 -> y1, else y2.  layout y[gr][o] (o fastest)
#pragma unroll
    for (int i = 0; i < 8; i++) {
        int r = gr0 + 8 * tr + i;
        float* dst = (tc < 8) ? (y1 + (size_t)r * 64 + 8 * tc)
                              : (y2 + (size_t)r * 64 + (8 * tc - 64));
        float4 s0, s1;
        s0.x = acc[i][0]; s0.y = acc[i][1]; s0.z = acc[i][2]; s0.w = acc[i][3];
        s1.x = acc[i][4]; s1.y = acc[i][5]; s1.z = acc[i][6]; s1.w = acc[i][7];
        *(float4*)dst = s0;
        *(float4*)(dst + 4) = s1;
    }
}

// ---------------------------------------------------------------------------
// k2: fused Gram + exact top-20 selection.
// 256 blocks (b, row-tile of 128) x 256 threads (4 waves).
// Streams 32 col-tiles of 128. Score s = 2*<p_n,p_m> - |p_m|^2 (row-constant
// -|p_n|^2 dropped: ordering-invariant). Selection: per-wave, 32 rows/wave,
// sorted top-20 (u64 keys, exact lower-index tie-break) in LDS, ballot-
// prefiltered wave-cooperative insertion.
// ---------------------------------------------------------------------------
__global__ __launch_bounds__(256) void k2_gram(const float* __restrict__ x,
                                               const float* __restrict__ sq,
                                               int* __restrict__ knn) {
    __shared__ float Xr[64][128];       // 32 KB  row-block points [c][r]
    __shared__ float Xc[64][128];       // 32 KB  col-tile points  [c][j]
    __shared__ float dst_s[128][64];    // 32 KB  scores, one 64-col half at a time
    __shared__ u64 wqS[4][32][20];      // 20 KB  per-wave per-row sorted top-20 keys
    __shared__ float sqc[128];

    int tid = threadIdx.x;
    int lane = tid & 63, w = tid >> 6;
    int b = blockIdx.x >> 5;
    int r0 = (blockIdx.x & 31) * 128;
    const float* xb = x + (size_t)b * (CDIM * NPTS);

    for (int k = 0; k < 32; k++) {
        int f = tid + 256 * k;
        int c = f >> 7, j = f & 127;
        Xr[c][j] = xb[c * NPTS + r0 + j];
    }
    for (int f = tid; f < 4 * 32 * 20; f += 256) ((u64*)wqS)[f] = 0ull;

    int tr = tid & 15, tc = tid >> 4;
    int myhalf = tc >> 3;               // which 64-col half this thread's cols land in
    int c0 = (8 * tc) & 63;

    for (int t = 0; t < 32; t++) {
        int n1 = t * 128;
        __syncthreads();                // prev tile's scans done -> Xc reusable
        for (int k = 0; k < 32; k++) {
            int f = tid + 256 * k;
            int c = f >> 7, j = f & 127;
            Xc[c][j] = xb[c * NPTS + n1 + j];
        }
        if (tid < 128) sqc[tid] = sq[b * NPTS + n1 + tid];
        __syncthreads();

        float acc[8][8];
#pragma unroll
        for (int i = 0; i < 8; i++)
#pragma unroll
            for (int j = 0; j < 8; j++) acc[i][j] = 0.f;

#pragma unroll 4
        for (int c = 0; c < 64; c++) {
            float a[8], bb[8];
            *(float4*)&a[0]  = *(const float4*)&Xr[c][8 * tr];
            *(float4*)&a[4]  = *(const float4*)&Xr[c][8 * tr + 4];
            *(float4*)&bb[0] = *(const float4*)&Xc[c][8 * tc];
            *(float4*)&bb[4] = *(const float4*)&Xc[c][8 * tc + 4];
#pragma unroll
            for (int i = 0; i < 8; i++)
#pragma unroll
                for (int j = 0; j < 8; j++) acc[i][j] = fmaf(a[i], bb[j], acc[i][j]);
        }

        for (int h = 0; h < 2; h++) {
            if (myhalf == h) {
                float sqv[8];
#pragma unroll
                for (int j = 0; j < 8; j++) sqv[j] = sqc[8 * tc + j];
#pragma unroll
                for (int i = 0; i < 8; i++) {
                    float4 s0, s1;
                    s0.x = fmaf(2.f, acc[i][0], -sqv[0]);
                    s0.y = fmaf(2.f, acc[i][1], -sqv[1]);
                    s0.z = fmaf(2.f, acc[i][2], -sqv[2]);
                    s0.w = fmaf(2.f, acc[i][3], -sqv[3]);
                    s1.x = fmaf(2.f, acc[i][4], -sqv[4]);
                    s1.y = fmaf(2.f, acc[i][5], -sqv[5]);
                    s1.z = fmaf(2.f, acc[i][6], -sqv[6]);
                    s1.w = fmaf(2.f, acc[i][7], -sqv[7]);
                    *(float4*)&dst_s[8 * tr + i][c0]     = s0;
                    *(float4*)&dst_s[8 * tr + i][c0 + 4] = s1;
                }
            }
            __syncthreads();            // scores ready

            // wave-cooperative scan: wave w owns rows [w*32, w*32+32)
            for (int r = 0; r < 32; r++) {
                int row = w * 32 + r;
                float v = dst_s[row][lane];
                int m = n1 + 64 * h + lane;
                unsigned u = __float_as_uint(v);
                u = (u & 0x80000000u) ? ~u : (u | 0x80000000u);
                u64 kv = ((u64)u << 32) | (u64)(~(unsigned)m);
                u64 thr = wqS[w][r][19];                // broadcast read
                u64 mask = __ballot(kv > thr);
                while (mask) {
                    int src = __ffsll(mask) - 1;
                    mask &= mask - 1;
                    u64 ck = __shfl(kv, src);
                    if (ck <= thr) continue;            // threshold rose; wave-uniform
                    u64 wv = (lane < 20) ? wqS[w][r][lane] : ~0ull;
                    u64 cm = __ballot(ck > wv);         // bits confined to lanes < 20
                    int pos = __ffsll(cm) - 1;          // insertion position (<= 19)
                    u64 sh = __shfl_up(wv, 1);
                    u64 nw = (lane == pos) ? ck : ((lane > pos) ? sh : wv);
                    if (lane < 20) wqS[w][r][lane] = nw;
                    thr = __shfl(nw, 19);
                }
            }
            __syncthreads();            // scans done before overwriting dst_s / Xc
        }
    }

    // emit indices (value order irrelevant downstream: max over k is order-free)
    for (int r = 0; r < 32; r++) {
        if (lane < 20) {
            u64 kk = wqS[w][r][lane];
            int m = (int)(~(unsigned)kk);
            knn[((size_t)b * NPTS + r0 + w * 32 + r) * KSEL + lane] = m;
        }
    }
}

// ---------------------------------------------------------------------------
// k3: out[b][o][n] = max_k y1[b][idx[n][k]][o] + y2[b][n][o] + bias[o]
// 512 blocks (b, 64-n tile) x 256 threads. Gather coalesced over o (=lane),
// transpose through padded LDS, store coalesced over n.
// ---------------------------------------------------------------------------
__global__ __launch_bounds__(256) void k3_out(const float* __restrict__ y1,
                                              const float* __restrict__ y2,
                                              const int* __restrict__ knn,
                                              const float* __restrict__ bias,
                                              float* __restrict__ out) {
    __shared__ float outT[64][65];   // [o][n-local], +1 pad
    __shared__ int idxT[64 * KSEL];
    int tid = threadIdx.x;
    int b = blockIdx.x >> 6;
    int n0 = (blockIdx.x & 63) * 64;

    for (int f = tid; f < 64 * KSEL; f += 256)
        idxT[f] = knn[((size_t)b * NPTS + n0) * KSEL + f];
    __syncthreads();

    int lane = tid & 63, w = tid >> 6;
    float bl = bias[lane];
    const float* y1b = y1 + (size_t)b * NPTS * 64;

    for (int i = 0; i < 16; i++) {
        int rr = w * 16 + i;
        float acc = -FLT_MAX;
#pragma unroll
        for (int k = 0; k < KSEL; k++) {
            int m = idxT[rr * KSEL + k];
            acc = fmaxf(acc, y1b[(size_t)m * 64 + lane]);
        }
        acc = acc + y2[((size_t)b * NPTS + n0 + rr) * 64 + lane] + bl;
        outT[lane][rr] = acc;
    }
    __syncthreads();

    int j = tid & 63, og = tid >> 6;
    for (int oo = 0; oo < 16; oo++) {
        int o = og * 16 + oo;
        out[((size_t)(b * 64 + o)) * NPTS + n0 + j] = outT[o][j];
    }
}

// ---------------------------------------------------------------------------
extern "C" void kernel_launch(void* const* d_in, const int* in_sizes, int n_in,
                              void* d_out, int out_size, void* d_ws, size_t ws_size,
                              hipStream_t stream) {
    const float* x    = (const float*)d_in[0];   // (8, 64, 4096)
    const float* W    = (const float*)d_in[1];   // (64, 128)
    const float* bias = (const float*)d_in[2];   // (64,)
    float* out = (float*)d_out;                  // (8, 64, 4096)
    float* ws = (float*)d_ws;                    // needs ~19.6 MB

    float* y1 = ws + OFF_Y1;
    float* y2 = ws + OFF_Y2;
    float* sq = ws + OFF_SQ;
    float* Wt = ws + OFF_WT;
    int* knn = (int*)(ws + OFF_KNN);

    hipLaunchKernelGGL(k0_wt,   dim3(32),  dim3(256), 0, stream, W, Wt);
    hipLaunchKernelGGL(k1_prep, dim3(256), dim3(256), 0, stream, x, Wt, y1, y2, sq);
    hipLaunchKernelGGL(k2_gram, dim3(256), dim3(256), 0, stream, x, sq, knn);
    hipLaunchKernelGGL(k3_out,  dim3(512), dim3(256), 0, stream, y1, y2, knn, bias, out);
}

// Round 2
// 1373.128 us; speedup vs baseline: 1.0012x; 1.0012x over previous
//
#include <hip/hip_runtime.h>
#include <float.h>

typedef unsigned long long u64;
typedef unsigned int u32;
typedef unsigned short u16;

#define NPTS 4096
#define CDIM 64
#define BATCH 8
#define KSEL 20

// float-unit offsets in ws (total 19.56 MB, same as round-1 footprint)
#define OFF_Y1 0
#define OFF_XTL (BATCH * NPTS * CDIM / 2)       // 1,048,576 floats (xt_h occupies [0, OFF_XTL))
#define OFF_Y2 (BATCH * NPTS * 64)              // 2,097,152
#define OFF_SQ (2 * BATCH * NPTS * 64)          // 4,194,304
#define OFF_WT (OFF_SQ + BATCH * NPTS)          // 4,227,072
#define OFF_KNN (OFF_WT + 64 * 128)             // 4,235,264 (int area)

typedef __attribute__((ext_vector_type(8))) short short8v;   // 8 bf16 (4 VGPR)
typedef __attribute__((ext_vector_type(16))) float float16v; // MFMA 32x32 acc

#define MFMA32(a, b, c) __builtin_amdgcn_mfma_f32_32x32x16_bf16(a, b, c, 0, 0, 0)

__device__ __forceinline__ u32 ordf(float f) {
    u32 u = __float_as_uint(f);
    return (u >> 31) ? ~u : (u | 0x80000000u);
}

// wave-cooperative insert into lane-distributed sorted-desc top-32 list (u32 keys).
// Lr: lane j (<32) holds j-th largest; lanes >=32 hold 0 sentinels.
__device__ __forceinline__ void insert32(u32& Lr, u32 ck, int lane) {
    u32 thr = __shfl(Lr, 31);
    u64 mask = __ballot(ck > thr);
    while (mask) {
        int src = __ffsll(mask) - 1;
        mask &= mask - 1;
        u32 cc = __shfl(ck, src);
        if (cc <= thr) continue;            // threshold rose (wave-uniform)
        u64 gt = __ballot(Lr > cc);
        int pos = __popcll(gt);             // insertion position (<=31)
        u32 sh = __shfl_up(Lr, 1);
        u32 nl = (lane == pos) ? cc : ((lane > pos) ? sh : Lr);
        if (lane < 32) Lr = nl;
        thr = __shfl(Lr, 31);
    }
}

// ---------------------------------------------------------------------------
// k0: W (64 x 128) -> Wt[c][o'] (64 x 128): o'<64: W1^T ; o'>=64: (W2-W1)^T
// ---------------------------------------------------------------------------
__global__ void k0_wt(const float* __restrict__ W, float* __restrict__ Wt) {
    int f = blockIdx.x * 256 + threadIdx.x;
    if (f >= 64 * 128) return;
    int c = f >> 7, o = f & 127;
    float v;
    if (o < 64) {
        v = W[o * 128 + c];
    } else {
        int oo = o - 64;
        v = W[oo * 128 + 64 + c] - W[oo * 128 + c];
    }
    Wt[f] = v;
}

// ---------------------------------------------------------------------------
// p1: transpose x[b][c][n] -> xtf[b][n][c] (fp32, in d_out), xt_h/xt_l (bf16
// hi/lo split, bit-exact RNE), and sq[n]. 512 blocks x 256 thr, 64n x 64c tile.
// ---------------------------------------------------------------------------
__global__ __launch_bounds__(256) void p1_prep(const float* __restrict__ x,
                                               float* __restrict__ xtf,
                                               u16* __restrict__ xth,
                                               u16* __restrict__ xtl,
                                               float* __restrict__ sq) {
    __shared__ float Xp[64][65];
    int tid = threadIdx.x;
    int b = blockIdx.x >> 6;
    int n0 = (blockIdx.x & 63) * 64;
    const float* xb = x + (size_t)b * (CDIM * NPTS);
    int j = tid & 63, cq = tid >> 6;
#pragma unroll
    for (int i = 0; i < 16; i++) {
        int c = cq * 16 + i;
        Xp[c][j] = xb[(size_t)c * NPTS + n0 + j];
    }
    __syncthreads();
    if (tid < 64) {
        float s = 0.f;
        for (int c = 0; c < 64; c++) { float v = Xp[c][tid]; s = fmaf(v, v, s); }
        sq[(size_t)b * NPTS + n0 + tid] = s;
    }
    int n = tid >> 2, c0 = (tid & 3) * 16;
    float vv[16];
#pragma unroll
    for (int i = 0; i < 16; i++) vv[i] = Xp[c0 + i][n];
    size_t rowb = ((size_t)b * NPTS + n0 + n) * 64 + c0;
#pragma unroll
    for (int q = 0; q < 4; q++) {
        float4 f;
        f.x = vv[4 * q]; f.y = vv[4 * q + 1]; f.z = vv[4 * q + 2]; f.w = vv[4 * q + 3];
        *(float4*)(xtf + rowb + 4 * q) = f;
    }
    u16 hb[16], lb[16];
#pragma unroll
    for (int i = 0; i < 16; i++) {
        float v = vv[i];
        u32 bv = __float_as_uint(v);
        u32 h = (bv + 0x7FFFu + ((bv >> 16) & 1u)) >> 16;    // RNE bf16
        float hf = __uint_as_float(h << 16);
        float lf = v - hf;
        u32 bl = __float_as_uint(lf);
        u32 lo = (bl + 0x7FFFu + ((bl >> 16) & 1u)) >> 16;
        hb[i] = (u16)h; lb[i] = (u16)lo;
    }
    uint4 H0, H1, L0, L1;
    H0.x = hb[0] | ((u32)hb[1] << 16);  H0.y = hb[2] | ((u32)hb[3] << 16);
    H0.z = hb[4] | ((u32)hb[5] << 16);  H0.w = hb[6] | ((u32)hb[7] << 16);
    H1.x = hb[8] | ((u32)hb[9] << 16);  H1.y = hb[10] | ((u32)hb[11] << 16);
    H1.z = hb[12] | ((u32)hb[13] << 16); H1.w = hb[14] | ((u32)hb[15] << 16);
    L0.x = lb[0] | ((u32)lb[1] << 16);  L0.y = lb[2] | ((u32)lb[3] << 16);
    L0.z = lb[4] | ((u32)lb[5] << 16);  L0.w = lb[6] | ((u32)lb[7] << 16);
    L1.x = lb[8] | ((u32)lb[9] << 16);  L1.y = lb[10] | ((u32)lb[11] << 16);
    L1.z = lb[12] | ((u32)lb[13] << 16); L1.w = lb[14] | ((u32)lb[15] << 16);
    *(uint4*)(xth + rowb) = H0;
    *(uint4*)(xth + rowb + 8) = H1;
    *(uint4*)(xtl + rowb) = L0;
    *(uint4*)(xtl + rowb + 8) = L1;
}

// ---------------------------------------------------------------------------
// k2: MFMA Gram (bf16 hi/lo split, 3 products) + register top-32 selection +
// exact fp32 rescore -> knn (top-20 indices). 256 blocks x 256 thr (4 waves).
// Block: batch = bid&7 (XCD-locality), rows r0..r0+127; wave w owns 32 rows.
// ---------------------------------------------------------------------------
__device__ __forceinline__ void stage_load(uint4 st[8], int tid, size_t bbase, int n1,
                                           const u16* __restrict__ xth,
                                           const u16* __restrict__ xtl) {
#pragma unroll
    for (int i = 0; i < 8; i++) {
        int G = tid + 256 * i;
        const u16* basep = (G >> 10) ? xtl : xth;
        int rr = (G >> 3) & 127, gg = G & 7;
        st[i] = *(const uint4*)(basep + (bbase + (size_t)(n1 + rr)) * 64 + gg * 8);
    }
}

__device__ __forceinline__ void stage_write(const uint4 st[8], int tid, char* pool) {
#pragma unroll
    for (int i = 0; i < 8; i++) {
        int G = tid + 256 * i;
        int arr = G >> 10, rr = (G >> 3) & 127, gg = G & 7;
        *(uint4*)(pool + arr * 16384 + rr * 128 + ((gg ^ (rr & 7)) << 4)) = st[i];
    }
}

__global__ __launch_bounds__(256, 1) void k2_gram(const u16* __restrict__ xth,
                                                  const u16* __restrict__ xtl,
                                                  const float* __restrict__ xtf,
                                                  const float* __restrict__ sq,
                                                  int* __restrict__ knn) {
    __shared__ char pool[32768];   // Bh 16K + Bl 16K (XOR-swizzled); reused as fp32 rows
    int tid = threadIdx.x;
    int lane = tid & 63, w = tid >> 6;
    int l31 = lane & 31, lh = lane >> 5;
    int b = blockIdx.x & 7;                 // same-batch blocks share an XCD's L2
    int r0 = (blockIdx.x >> 3) * 128;
    size_t bbase = (size_t)b * NPTS;

    // A fragments: rows r0+32w..+31, K=64 in 4 steps of 16 (kept in regs all run)
    short8v Ah[4], Al[4];
    {
        const u16* pa = xth + (bbase + r0 + 32 * w + l31) * 64 + 8 * lh;
        const u16* pl = xtl + (bbase + r0 + 32 * w + l31) * 64 + 8 * lh;
#pragma unroll
        for (int s = 0; s < 4; s++) {
            Ah[s] = *(const short8v*)(pa + 16 * s);
            Al[s] = *(const short8v*)(pl + 16 * s);
        }
    }

    u32 L[32];
#pragma unroll
    for (int i = 0; i < 32; i++) L[i] = 0u;

    uint4 st[8];
    stage_load(st, tid, bbase, 0, xth, xtl);
    stage_write(st, tid, pool);
    __syncthreads();

    for (int t = 0; t < 32; t++) {
        int n1 = t * 128;
        if (t < 31) stage_load(st, tid, bbase, n1 + 128, xth, xtl);  // overlap w/ compute
        float sq0 = sq[bbase + n1 + lane];
        float sq1 = sq[bbase + n1 + 64 + lane];

#pragma unroll
        for (int p = 0; p < 2; p++) {       // half p: out-tiles 2p,2p+1 (cols 64p..64p+63)
            float16v a0 = {}, a1 = {};
#pragma unroll
            for (int s = 0; s < 4; s++) {
                int rA = 64 * p + l31, rB = rA + 32;
                int gx = 2 * s + lh;
                int oA = rA * 128 + ((gx ^ (rA & 7)) << 4);
                int oB = rB * 128 + ((gx ^ (rB & 7)) << 4);
                short8v bh0 = *(const short8v*)(pool + oA);
                short8v bl0 = *(const short8v*)(pool + 16384 + oA);
                short8v bh1 = *(const short8v*)(pool + oB);
                short8v bl1 = *(const short8v*)(pool + 16384 + oB);
                a0 = MFMA32(Ah[s], bh0, a0);
                a0 = MFMA32(Al[s], bh0, a0);
                a0 = MFMA32(Ah[s], bl0, a0);
                a1 = MFMA32(Ah[s], bh1, a1);
                a1 = MFMA32(Al[s], bh1, a1);
                a1 = MFMA32(Ah[s], bl1, a1);
            }
            float sqv = p ? sq1 : sq0;
            u32 colk = (u32)(n1 + 64 * p + lane);
#pragma unroll
            for (int r = 0; r < 16; r++) {
                int R0 = (r & 3) + 8 * (r >> 2);     // m101 C/D row map
                float e0 = a0[r], e1 = a1[r];
                float xswap0 = __shfl_xor(e1, 32);
                float xswap1 = __shfl_xor(e0, 32);
                float v0 = (lane < 32) ? e0 : xswap0;  // row R0,   col = 64p+lane
                float v1 = (lane < 32) ? xswap1 : e1;  // row R0+4, col = 64p+lane
                float s0 = fmaf(2.f, v0, -sqv);
                float s1 = fmaf(2.f, v1, -sqv);
                u32 k0 = (ordf(s0) & 0xFFFF0000u) | colk;
                u32 k1 = (ordf(s1) & 0xFFFF0000u) | colk;
                insert32(L[R0], k0, lane);
                insert32(L[R0 + 4], k1, lane);
            }
        }
        __syncthreads();                    // all waves done reading pool
        if (t < 31) {
            stage_write(st, tid, pool);
            __syncthreads();
        }
    }

    // ---- exact fp32 rescore of the 32 candidates per row, pick top-20 ----
    float* poolF = (float*)pool;
    // stage this wave's 32 fp32 rows (8 KB) into its pool quarter
#pragma unroll
    for (int rr = 0; rr < 4; rr++) {
        int row = rr * 8 + (lane >> 3);
        int cg = lane & 7;
        const float4* src = (const float4*)(xtf + (bbase + r0 + 32 * w + row) * 64 + cg * 8);
        float4 v0 = src[0], v1 = src[1];
        float4* dst = (float4*)(poolF + w * 2048 + row * 64 + cg * 8);
        dst[0] = v0; dst[1] = v1;
    }

#pragma unroll
    for (int r = 0; r < 32; r++) {
        float4 xr = *(const float4*)(poolF + w * 2048 + r * 64 + (lane & 15) * 4);
        u64 kE = 0;
        for (int i = 0; i < 8; i++) {       // 4 candidates per iter (16-lane groups)
            int cs = 4 * i + (lane >> 4);
            u32 Le = __shfl(L[r], cs);
            int m = (int)(Le & 0xFFFFu);
            const float4* pm = (const float4*)(xtf + (bbase + m) * 64 + (lane & 15) * 4);
            float4 xm = *pm;
            float d = xm.x * xr.x;
            d = fmaf(xm.y, xr.y, d);
            d = fmaf(xm.z, xr.z, d);
            d = fmaf(xm.w, xr.w, d);
            d += __shfl_xor(d, 1);
            d += __shfl_xor(d, 2);
            d += __shfl_xor(d, 4);
            d += __shfl_xor(d, 8);
            float se = fmaf(2.f, d, -sq[bbase + m]);
            u64 kc = ((u64)ordf(se) << 32) | (u32)(~(u32)m);
            u64 got = __shfl(kc, (lane & 3) << 4);
            kE = ((lane >> 2) == i) ? got : kE;
        }
        // bitonic desc sort within 32-lane halves (upper half = 0 sentinels)
#pragma unroll
        for (int k = 2; k <= 32; k <<= 1) {
#pragma unroll
            for (int jj = k >> 1; jj >= 1; jj >>= 1) {
                u64 pk = __shfl_xor(kE, jj);
                bool up = ((lane & k) == 0);
                bool lower = ((lane & jj) == 0);
                u64 mx = (kE > pk) ? kE : pk;
                u64 mn = (kE > pk) ? pk : kE;
                kE = (lower == up) ? mx : mn;
            }
        }
        if (lane < KSEL)
            knn[(bbase + r0 + 32 * w + r) * KSEL + lane] = (int)(~(u32)kE);
    }
}

// ---------------------------------------------------------------------------
// k1: y1[n][o] = sum_c x[b][c][n] * Wt[c][o] (o'<64); y2: o'>=64. (round-1, -sq)
// ---------------------------------------------------------------------------
__global__ __launch_bounds__(256) void k1_prep(const float* __restrict__ x,
                                               const float* __restrict__ Wtg,
                                               float* __restrict__ y1,
                                               float* __restrict__ y2) {
    __shared__ float Xt[64][128];
    __shared__ float Wt[64][128];
    int tid = threadIdx.x;
    int gr0 = blockIdx.x * 128;
    int b = gr0 >> 12;
    int n0 = gr0 & 4095;
    const float* xb = x + (size_t)b * (CDIM * NPTS) + n0;

    for (int k = 0; k < 32; k++) {
        int f = tid + 256 * k;
        int c = f >> 7, j = f & 127;
        Xt[c][j] = xb[(size_t)c * NPTS + j];
        ((float*)Wt)[f] = Wtg[f];
    }
    __syncthreads();

    int tr = tid & 15, tc = tid >> 4;
    float acc[8][8];
#pragma unroll
    for (int i = 0; i < 8; i++)
#pragma unroll
        for (int j = 0; j < 8; j++) acc[i][j] = 0.f;

#pragma unroll 4
    for (int c = 0; c < 64; c++) {
        float a[8], bb[8];
        *(float4*)&a[0]  = *(const float4*)&Xt[c][8 * tr];
        *(float4*)&a[4]  = *(const float4*)&Xt[c][8 * tr + 4];
        *(float4*)&bb[0] = *(const float4*)&Wt[c][8 * tc];
        *(float4*)&bb[4] = *(const float4*)&Wt[c][8 * tc + 4];
#pragma unroll
        for (int i = 0; i < 8; i++)
#pragma unroll
            for (int j = 0; j < 8; j++) acc[i][j] = fmaf(a[i], bb[j], acc[i][j]);
    }

#pragma unroll
    for (int i = 0; i < 8; i++) {
        int r = gr0 + 8 * tr + i;
        float* dst = (tc < 8) ? (y1 + (size_t)r * 64 + 8 * tc)
                              : (y2 + (size_t)r * 64 + (8 * tc - 64));
        float4 s0, s1;
        s0.x = acc[i][0]; s0.y = acc[i][1]; s0.z = acc[i][2]; s0.w = acc[i][3];
        s1.x = acc[i][4]; s1.y = acc[i][5]; s1.z = acc[i][6]; s1.w = acc[i][7];
        *(float4*)dst = s0;
        *(float4*)(dst + 4) = s1;
    }
}

// ---------------------------------------------------------------------------
// k3: out[b][o][n] = max_k y1[b][idx[n][k]][o] + y2[b][n][o] + bias[o]
// ---------------------------------------------------------------------------
__global__ __launch_bounds__(256) void k3_out(const float* __restrict__ y1,
                                              const float* __restrict__ y2,
                                              const int* __restrict__ knn,
                                              const float* __restrict__ bias,
                                              float* __restrict__ out) {
    __shared__ float outT[64][65];
    __shared__ int idxT[64 * KSEL];
    int tid = threadIdx.x;
    int b = blockIdx.x >> 6;
    int n0 = (blockIdx.x & 63) * 64;

    for (int f = tid; f < 64 * KSEL; f += 256)
        idxT[f] = knn[((size_t)b * NPTS + n0) * KSEL + f];
    __syncthreads();

    int lane = tid & 63, w = tid >> 6;
    float bl = bias[lane];
    const float* y1b = y1 + (size_t)b * NPTS * 64;

    for (int i = 0; i < 16; i++) {
        int rr = w * 16 + i;
        float acc = -FLT_MAX;
#pragma unroll
        for (int k = 0; k < KSEL; k++) {
            int m = idxT[rr * KSEL + k];
            acc = fmaxf(acc, y1b[(size_t)m * 64 + lane]);
        }
        acc = acc + y2[((size_t)b * NPTS + n0 + rr) * 64 + lane] + bl;
        outT[lane][rr] = acc;
    }
    __syncthreads();

    int j = tid & 63, og = tid >> 6;
    for (int oo = 0; oo < 16; oo++) {
        int o = og * 16 + oo;
        out[((size_t)(b * 64 + o)) * NPTS + n0 + j] = outT[o][j];
    }
}

// ---------------------------------------------------------------------------
extern "C" void kernel_launch(void* const* d_in, const int* in_sizes, int n_in,
                              void* d_out, int out_size, void* d_ws, size_t ws_size,
                              hipStream_t stream) {
    const float* x    = (const float*)d_in[0];   // (8, 64, 4096)
    const float* W    = (const float*)d_in[1];   // (64, 128)
    const float* bias = (const float*)d_in[2];   // (64,)
    float* out = (float*)d_out;                  // (8, 64, 4096)
    float* ws = (float*)d_ws;

    u16* xth   = (u16*)ws;                  // 4 MB  (dies before k1)
    u16* xtl   = (u16*)(ws + OFF_XTL);      // 4 MB  (dies before k1)
    float* y1  = ws + OFF_Y1;               // overlays xth/xtl after k2
    float* y2  = ws + OFF_Y2;
    float* sq  = ws + OFF_SQ;
    float* Wt  = ws + OFF_WT;
    int* knn   = (int*)(ws + OFF_KNN);
    float* xtf = (float*)d_out;             // fp32 transposed copy; k3 overwrites

    hipLaunchKernelGGL(k0_wt,   dim3(32),  dim3(256), 0, stream, W, Wt);
    hipLaunchKernelGGL(p1_prep, dim3(512), dim3(256), 0, stream, x, xtf, xth, xtl, sq);
    hipLaunchKernelGGL(k2_gram, dim3(256), dim3(256), 0, stream, xth, xtl, xtf, sq, knn);
    hipLaunchKernelGGL(k1_prep, dim3(256), dim3(256), 0, stream, x, Wt, y1, y2);
    hipLaunchKernelGGL(k3_out,  dim3(512), dim3(256), 0, stream, y1, y2, knn, bias, out);
}

// Round 3
// 536.465 us; speedup vs baseline: 2.5626x; 2.5596x over previous
//
#include <hip/hip_runtime.h>
#include <float.h>

typedef unsigned long long u64;
typedef unsigned int u32;
typedef unsigned short u16;

#define NPTS 4096
#define CDIM 64
#define BATCH 8
#define KSEL 20

// float-unit offsets in ws (total ~19.6 MB, same footprint as rounds 1-2)
#define OFF_Y1 0
#define OFF_XTL (BATCH * NPTS * CDIM / 2)       // xth in [0,4MB), xtl in [4MB,8MB)
#define OFF_Y2 (BATCH * NPTS * 64)              // [8MB,16MB): cand during k2/k2b, y2 after
#define OFF_SQ (2 * BATCH * NPTS * 64)
#define OFF_WT (OFF_SQ + BATCH * NPTS)
#define OFF_KNN (OFF_WT + 64 * 128)

typedef __attribute__((ext_vector_type(8))) short short8v;   // 8 bf16 (4 VGPR)
typedef __attribute__((ext_vector_type(16))) float float16v; // MFMA 32x32 acc

#define MFMA32(a, b, c) __builtin_amdgcn_mfma_f32_32x32x16_bf16(a, b, c, 0, 0, 0)

__device__ __forceinline__ u32 ordf(float f) {
    u32 u = __float_as_uint(f);
    return (u >> 31) ? ~u : (u | 0x80000000u);
}
__device__ __forceinline__ u32 umaxu(u32 a, u32 b) { return a > b ? a : b; }
__device__ __forceinline__ u32 uminu(u32 a, u32 b) { return a < b ? a : b; }

__device__ __forceinline__ u32 max16(const u32 c[16]) {
    u32 a0 = umaxu(c[0], c[1]),  a1 = umaxu(c[2], c[3]);
    u32 a2 = umaxu(c[4], c[5]),  a3 = umaxu(c[6], c[7]);
    u32 a4 = umaxu(c[8], c[9]),  a5 = umaxu(c[10], c[11]);
    u32 a6 = umaxu(c[12], c[13]), a7 = umaxu(c[14], c[15]);
    a0 = umaxu(a0, a1); a2 = umaxu(a2, a3); a4 = umaxu(a4, a5); a6 = umaxu(a6, a7);
    return umaxu(umaxu(a0, a2), umaxu(a4, a6));
}

// ---------------------------------------------------------------------------
// k0: W (64 x 128) -> Wt[c][o'] (64 x 128): o'<64: W1^T ; o'>=64: (W2-W1)^T
// ---------------------------------------------------------------------------
__global__ void k0_wt(const float* __restrict__ W, float* __restrict__ Wt) {
    int f = blockIdx.x * 256 + threadIdx.x;
    if (f >= 64 * 128) return;
    int c = f >> 7, o = f & 127;
    float v;
    if (o < 64) {
        v = W[o * 128 + c];
    } else {
        int oo = o - 64;
        v = W[oo * 128 + 64 + c] - W[oo * 128 + c];
    }
    Wt[f] = v;
}

// ---------------------------------------------------------------------------
// p1: transpose x[b][c][n] -> xtf[b][n][c] (fp32, in d_out), xt_h/xt_l (bf16
// hi/lo split, RNE), and sq[n]. 512 blocks x 256 thr, 64n x 64c tile.
// (validated in round 2)
// ---------------------------------------------------------------------------
__global__ __launch_bounds__(256) void p1_prep(const float* __restrict__ x,
                                               float* __restrict__ xtf,
                                               u16* __restrict__ xth,
                                               u16* __restrict__ xtl,
                                               float* __restrict__ sq) {
    __shared__ float Xp[64][65];
    int tid = threadIdx.x;
    int b = blockIdx.x >> 6;
    int n0 = (blockIdx.x & 63) * 64;
    const float* xb = x + (size_t)b * (CDIM * NPTS);
    int j = tid & 63, cq = tid >> 6;
#pragma unroll
    for (int i = 0; i < 16; i++) {
        int c = cq * 16 + i;
        Xp[c][j] = xb[(size_t)c * NPTS + n0 + j];
    }
    __syncthreads();
    if (tid < 64) {
        float s = 0.f;
        for (int c = 0; c < 64; c++) { float v = Xp[c][tid]; s = fmaf(v, v, s); }
        sq[(size_t)b * NPTS + n0 + tid] = s;
    }
    int n = tid >> 2, c0 = (tid & 3) * 16;
    float vv[16];
#pragma unroll
    for (int i = 0; i < 16; i++) vv[i] = Xp[c0 + i][n];
    size_t rowb = ((size_t)b * NPTS + n0 + n) * 64 + c0;
#pragma unroll
    for (int q = 0; q < 4; q++) {
        float4 f;
        f.x = vv[4 * q]; f.y = vv[4 * q + 1]; f.z = vv[4 * q + 2]; f.w = vv[4 * q + 3];
        *(float4*)(xtf + rowb + 4 * q) = f;
    }
    u16 hb[16], lb[16];
#pragma unroll
    for (int i = 0; i < 16; i++) {
        float v = vv[i];
        u32 bv = __float_as_uint(v);
        u32 h = (bv + 0x7FFFu + ((bv >> 16) & 1u)) >> 16;    // RNE bf16
        float hf = __uint_as_float(h << 16);
        float lf = v - hf;
        u32 bl = __float_as_uint(lf);
        u32 lo = (bl + 0x7FFFu + ((bl >> 16) & 1u)) >> 16;
        hb[i] = (u16)h; lb[i] = (u16)lo;
    }
    uint4 H0, H1, L0, L1;
    H0.x = hb[0] | ((u32)hb[1] << 16);  H0.y = hb[2] | ((u32)hb[3] << 16);
    H0.z = hb[4] | ((u32)hb[5] << 16);  H0.w = hb[6] | ((u32)hb[7] << 16);
    H1.x = hb[8] | ((u32)hb[9] << 16);  H1.y = hb[10] | ((u32)hb[11] << 16);
    H1.z = hb[12] | ((u32)hb[13] << 16); H1.w = hb[14] | ((u32)hb[15] << 16);
    L0.x = lb[0] | ((u32)lb[1] << 16);  L0.y = lb[2] | ((u32)lb[3] << 16);
    L0.z = lb[4] | ((u32)lb[5] << 16);  L0.w = lb[6] | ((u32)lb[7] << 16);
    L1.x = lb[8] | ((u32)lb[9] << 16);  L1.y = lb[10] | ((u32)lb[11] << 16);
    L1.z = lb[12] | ((u32)lb[13] << 16); L1.w = lb[14] | ((u32)lb[15] << 16);
    *(uint4*)(xth + rowb) = H0;
    *(uint4*)(xth + rowb + 8) = H1;
    *(uint4*)(xtl + rowb) = L0;
    *(uint4*)(xtl + rowb + 8) = L1;
}

// ---------------------------------------------------------------------------
// k2: MFMA Gram (bf16 hi/lo, 3 products) over a (128-row x 1024-col) chunk +
// per-lane exact register top-32 (quantized keys) -> cand cols (u16).
// Grid 1024 = 8 b x 32 rowtiles x 4 chunks; 256 thr (4 waves); 3 blocks/CU.
// Lane owns (row = lane&31, col-class = bit4 of col matching lane>=32).
// ---------------------------------------------------------------------------
__device__ __forceinline__ void stage_load(uint4 st[8], int tid, size_t bbase, int n1,
                                           const u16* __restrict__ xth,
                                           const u16* __restrict__ xtl) {
#pragma unroll
    for (int i = 0; i < 8; i++) {
        int G = tid + 256 * i;
        const u16* basep = (G >> 10) ? xtl : xth;
        int rr = (G >> 3) & 127, gg = G & 7;
        st[i] = *(const uint4*)(basep + (bbase + (size_t)(n1 + rr)) * 64 + gg * 8);
    }
}

__device__ __forceinline__ void stage_write(const uint4 st[8], int tid, char* pool) {
#pragma unroll
    for (int i = 0; i < 8; i++) {
        int G = tid + 256 * i;
        int arr = G >> 10, rr = (G >> 3) & 127, gg = G & 7;
        *(uint4*)(pool + arr * 16384 + rr * 128 + ((gg ^ (rr & 7)) << 4)) = st[i];
    }
}

// scan one 32x32 acc tile: write scores to per-wave T, read back row-per-lane,
// insert into per-lane sorted-32 (u32 keys) via max-extract + min/max chain.
__device__ __forceinline__ void scan_acc(const float16v& A, float sqv, int basec,
                                         float (*Tw)[36], int l31, int lh,
                                         u32 (&L)[32]) {
#pragma unroll
    for (int r = 0; r < 16; r++) {
        int R0 = (r & 3) + 8 * (r >> 2) + 4 * lh;    // m101 C/D row map
        Tw[R0][l31] = fmaf(2.f, A[r], -sqv);
    }
    // compiler inserts lgkmcnt wait for the LDS RAW below (same wave)
    u32 c[16];
    int cc = 16 * lh;
#pragma unroll
    for (int q = 0; q < 4; q++) {
        float4 v = *(const float4*)&Tw[l31][cc + 4 * q];
        c[4 * q + 0] = (ordf(v.x) & 0xFFFF0000u) | (u32)(basec + cc + 4 * q + 0);
        c[4 * q + 1] = (ordf(v.y) & 0xFFFF0000u) | (u32)(basec + cc + 4 * q + 1);
        c[4 * q + 2] = (ordf(v.z) & 0xFFFF0000u) | (u32)(basec + cc + 4 * q + 2);
        c[4 * q + 3] = (ordf(v.w) & 0xFFFF0000u) | (u32)(basec + cc + 4 * q + 3);
    }
    u32 m = max16(c);
    while (__any(m > L[31])) {
        u32 ins = (m > L[31]) ? m : 0u;     // 0 = neutral (real keys > 0)
#pragma unroll
        for (int i = 31; i >= 1; --i) L[i] = umaxu(uminu(L[i - 1], ins), L[i]);
        L[0] = umaxu(L[0], ins);
#pragma unroll
        for (int j = 0; j < 16; j++) c[j] = (c[j] == m) ? 0u : c[j];
        m = max16(c);
    }
}

__global__ __launch_bounds__(256, 3) void k2_gram(const u16* __restrict__ xth,
                                                  const u16* __restrict__ xtl,
                                                  const float* __restrict__ sq,
                                                  u16* __restrict__ cand) {
    __shared__ char pool[32768];       // B-tile: hi 16K + lo 16K, XOR-swizzled
    __shared__ float T[4][32][36];     // per-wave score transpose (18 KB)
    int tid = threadIdx.x;
    int lane = tid & 63, w = tid >> 6;
    int l31 = lane & 31, lh = lane >> 5;
    int b = blockIdx.x & 7;                   // same batch -> same XCD (L2 locality)
    int rt = (blockIdx.x >> 3) & 31;
    int ch = blockIdx.x >> 8;
    int r0 = rt * 128;
    int cb = ch * 1024;
    size_t bbase = (size_t)b * NPTS;

    // A fragments: rows r0+32w..+31, K=64 in 4 steps of 16 (in regs all run)
    short8v Ah[4], Al[4];
    {
        const u16* pa = xth + (bbase + r0 + 32 * w + l31) * 64 + 8 * lh;
        const u16* pl = xtl + (bbase + r0 + 32 * w + l31) * 64 + 8 * lh;
#pragma unroll
        for (int s = 0; s < 4; s++) {
            Ah[s] = *(const short8v*)(pa + 16 * s);
            Al[s] = *(const short8v*)(pl + 16 * s);
        }
    }

    u32 L[32];
#pragma unroll
    for (int i = 0; i < 32; i++) L[i] = 0u;

    uint4 st[8];
    stage_load(st, tid, bbase, cb, xth, xtl);
    stage_write(st, tid, pool);
    __syncthreads();

    for (int t = 0; t < 8; t++) {
        int n1 = cb + t * 128;
        if (t < 7) stage_load(st, tid, bbase, n1 + 128, xth, xtl);   // overlap

#pragma unroll
        for (int p = 0; p < 2; p++) {
            float16v a0 = {}, a1 = {};
#pragma unroll
            for (int s = 0; s < 4; s++) {
                int rA = 64 * p + l31, rB = rA + 32;
                int gx = 2 * s + lh;
                int oA = rA * 128 + ((gx ^ (rA & 7)) << 4);
                int oB = rB * 128 + ((gx ^ (rB & 7)) << 4);
                short8v bh0 = *(const short8v*)(pool + oA);
                short8v bl0 = *(const short8v*)(pool + 16384 + oA);
                short8v bh1 = *(const short8v*)(pool + oB);
                short8v bl1 = *(const short8v*)(pool + 16384 + oB);
                a0 = MFMA32(Ah[s], bh0, a0);
                a0 = MFMA32(Al[s], bh0, a0);
                a0 = MFMA32(Ah[s], bl0, a0);
                a1 = MFMA32(Ah[s], bh1, a1);
                a1 = MFMA32(Al[s], bh1, a1);
                a1 = MFMA32(Ah[s], bl1, a1);
            }
            scan_acc(a0, sq[bbase + n1 + 64 * p + l31],      n1 + 64 * p,      T[w], l31, lh, L);
            scan_acc(a1, sq[bbase + n1 + 64 * p + 32 + l31], n1 + 64 * p + 32, T[w], l31, lh, L);
        }
        __syncthreads();                 // all waves done reading pool
        if (t < 7) {
            stage_write(st, tid, pool);
            __syncthreads();
        }
    }

    // merge the row's two class-lists: top-32 of union = max(A_i, B_{31-i})
    u32 M[32];
#pragma unroll
    for (int i = 0; i < 32; i++) {
        u32 pv = __shfl_xor(L[31 - i], 32);
        M[i] = umaxu(L[i], pv);
    }
    if (lane < 32) {
        u16* cr = cand + (bbase + r0 + 32 * w + l31) * 128 + ch * 32;
#pragma unroll
        for (int q = 0; q < 16; q++) {
            u32 pk = (M[2 * q] & 0xFFFFu) | ((M[2 * q + 1] & 0xFFFFu) << 16);
            *(u32*)(cr + 2 * q) = pk;
        }
    }
}

// ---------------------------------------------------------------------------
// k2b: exact fp32 rescore of 128 candidates/row + distributed bitonic top-20.
// 8192 blocks x 256 thr; wave = one row; lane handles 2 candidates.
// ---------------------------------------------------------------------------
__global__ __launch_bounds__(256) void k2b_rescore(const float* __restrict__ xtf,
                                                   const float* __restrict__ sq,
                                                   const u16* __restrict__ cand,
                                                   int* __restrict__ knn) {
    __shared__ float xr[4][64];
    int tid = threadIdx.x;
    int lane = tid & 63, w = tid >> 6;
    size_t row = (size_t)blockIdx.x * 4 + w;
    size_t bbase = (row >> 12) << 12;

    if (lane < 16)
        *(float4*)&xr[w][lane * 4] = *(const float4*)(xtf + row * 64 + lane * 4);
    __syncthreads();

    u32 cw = *(const u32*)(cand + row * 128 + 2 * lane);
    int m0 = (int)(cw & 0xFFFFu), m1 = (int)(cw >> 16);

    float d0 = 0.f, d1 = 0.f;
    const float* p0 = xtf + (bbase + m0) * 64;
    const float* p1 = xtf + (bbase + m1) * 64;
#pragma unroll
    for (int q = 0; q < 16; q++) {
        float4 xq = *(const float4*)&xr[w][4 * q];
        float4 v0 = *(const float4*)(p0 + 4 * q);
        float4 v1 = *(const float4*)(p1 + 4 * q);
        d0 = fmaf(v0.x, xq.x, d0); d0 = fmaf(v0.y, xq.y, d0);
        d0 = fmaf(v0.z, xq.z, d0); d0 = fmaf(v0.w, xq.w, d0);
        d1 = fmaf(v1.x, xq.x, d1); d1 = fmaf(v1.y, xq.y, d1);
        d1 = fmaf(v1.z, xq.z, d1); d1 = fmaf(v1.w, xq.w, d1);
    }
    float s0 = fmaf(2.f, d0, -sq[bbase + m0]);
    float s1 = fmaf(2.f, d1, -sq[bbase + m1]);
    u64 kA = ((u64)ordf(s0) << 32) | (u32)(~(u32)m0);
    u64 kB = ((u64)ordf(s1) << 32) | (u32)(~(u32)m1);

    // full 64-lane descending bitonic sort of kA and of kB
#pragma unroll
    for (u32 k = 2; k <= 64; k <<= 1) {
#pragma unroll
        for (u32 j2 = k >> 1; j2 >= 1; j2 >>= 1) {
            bool up = ((lane & k) == 0);
            bool lower = ((lane & j2) == 0);
            u64 pA = __shfl_xor(kA, j2);
            u64 mxA = (kA > pA) ? kA : pA, mnA = (kA > pA) ? pA : kA;
            kA = (lower == up) ? mxA : mnA;
            u64 pB = __shfl_xor(kB, j2);
            u64 mxB = (kB > pB) ? kB : pB, mnB = (kB > pB) ? pB : kB;
            kB = (lower == up) ? mxB : mnB;
        }
    }
    // [kA desc | reverse(kB) asc] is 128-bitonic; keep elementwise max (top-64)
    u64 rB = __shfl(kB, 63 - lane);
    u64 M = (kA > rB) ? kA : rB;
    // descending bitonic merge of the (bitonic) top-64
#pragma unroll
    for (u32 j2 = 32; j2 >= 1; j2 >>= 1) {
        u64 p = __shfl_xor(M, j2);
        bool lower = ((lane & j2) == 0);
        u64 mx = (M > p) ? M : p, mn = (M > p) ? p : M;
        M = lower ? mx : mn;
    }
    if (lane < KSEL)
        knn[row * KSEL + lane] = (int)(~(u32)M);
}

// ---------------------------------------------------------------------------
// k1: y1[n][o] = sum_c x[b][c][n] * Wt[c][o] (o'<64); y2: o'>=64. (validated)
// ---------------------------------------------------------------------------
__global__ __launch_bounds__(256) void k1_prep(const float* __restrict__ x,
                                               const float* __restrict__ Wtg,
                                               float* __restrict__ y1,
                                               float* __restrict__ y2) {
    __shared__ float Xt[64][128];
    __shared__ float Wt[64][128];
    int tid = threadIdx.x;
    int gr0 = blockIdx.x * 128;
    int b = gr0 >> 12;
    int n0 = gr0 & 4095;
    const float* xb = x + (size_t)b * (CDIM * NPTS) + n0;

    for (int k = 0; k < 32; k++) {
        int f = tid + 256 * k;
        int c = f >> 7, j = f & 127;
        Xt[c][j] = xb[(size_t)c * NPTS + j];
        ((float*)Wt)[f] = Wtg[f];
    }
    __syncthreads();

    int tr = tid & 15, tc = tid >> 4;
    float acc[8][8];
#pragma unroll
    for (int i = 0; i < 8; i++)
#pragma unroll
        for (int j = 0; j < 8; j++) acc[i][j] = 0.f;

#pragma unroll 4
    for (int c = 0; c < 64; c++) {
        float a[8], bb[8];
        *(float4*)&a[0]  = *(const float4*)&Xt[c][8 * tr];
        *(float4*)&a[4]  = *(const float4*)&Xt[c][8 * tr + 4];
        *(float4*)&bb[0] = *(const float4*)&Wt[c][8 * tc];
        *(float4*)&bb[4] = *(const float4*)&Wt[c][8 * tc + 4];
#pragma unroll
        for (int i = 0; i < 8; i++)
#pragma unroll
            for (int j = 0; j < 8; j++) acc[i][j] = fmaf(a[i], bb[j], acc[i][j]);
    }

#pragma unroll
    for (int i = 0; i < 8; i++) {
        int r = gr0 + 8 * tr + i;
        float* dst = (tc < 8) ? (y1 + (size_t)r * 64 + 8 * tc)
                              : (y2 + (size_t)r * 64 + (8 * tc - 64));
        float4 s0, s1;
        s0.x = acc[i][0]; s0.y = acc[i][1]; s0.z = acc[i][2]; s0.w = acc[i][3];
        s1.x = acc[i][4]; s1.y = acc[i][5]; s1.z = acc[i][6]; s1.w = acc[i][7];
        *(float4*)dst = s0;
        *(float4*)(dst + 4) = s1;
    }
}

// ---------------------------------------------------------------------------
// k3: out[b][o][n] = max_k y1[b][idx[n][k]][o] + y2[b][n][o] + bias[o]
// ---------------------------------------------------------------------------
__global__ __launch_bounds__(256) void k3_out(const float* __restrict__ y1,
                                              const float* __restrict__ y2,
                                              const int* __restrict__ knn,
                                              const float* __restrict__ bias,
                                              float* __restrict__ out) {
    __shared__ float outT[64][65];
    __shared__ int idxT[64 * KSEL];
    int tid = threadIdx.x;
    int b = blockIdx.x >> 6;
    int n0 = (blockIdx.x & 63) * 64;

    for (int f = tid; f < 64 * KSEL; f += 256)
        idxT[f] = knn[((size_t)b * NPTS + n0) * KSEL + f];
    __syncthreads();

    int lane = tid & 63, w = tid >> 6;
    float bl = bias[lane];
    const float* y1b = y1 + (size_t)b * NPTS * 64;

    for (int i = 0; i < 16; i++) {
        int rr = w * 16 + i;
        float acc = -FLT_MAX;
#pragma unroll
        for (int k = 0; k < KSEL; k++) {
            int m = idxT[rr * KSEL + k];
            acc = fmaxf(acc, y1b[(size_t)m * 64 + lane]);
        }
        acc = acc + y2[((size_t)b * NPTS + n0 + rr) * 64 + lane] + bl;
        outT[lane][rr] = acc;
    }
    __syncthreads();

    int j = tid & 63, og = tid >> 6;
    for (int oo = 0; oo < 16; oo++) {
        int o = og * 16 + oo;
        out[((size_t)(b * 64 + o)) * NPTS + n0 + j] = outT[o][j];
    }
}

// ---------------------------------------------------------------------------
extern "C" void kernel_launch(void* const* d_in, const int* in_sizes, int n_in,
                              void* d_out, int out_size, void* d_ws, size_t ws_size,
                              hipStream_t stream) {
    const float* x    = (const float*)d_in[0];   // (8, 64, 4096)
    const float* W    = (const float*)d_in[1];   // (64, 128)
    const float* bias = (const float*)d_in[2];   // (64,)
    float* out = (float*)d_out;                  // (8, 64, 4096)
    float* ws = (float*)d_ws;

    u16* xth   = (u16*)ws;                  // [0,4MB)   dies before k1
    u16* xtl   = (u16*)(ws + OFF_XTL);      // [4,8MB)   dies before k1
    u16* candb = (u16*)(ws + OFF_Y2);       // [8,16MB)  dies before k1 writes y2
    float* y1  = ws + OFF_Y1;
    float* y2  = ws + OFF_Y2;
    float* sq  = ws + OFF_SQ;
    float* Wt  = ws + OFF_WT;
    int* knn   = (int*)(ws + OFF_KNN);
    float* xtf = (float*)d_out;             // fp32 transposed copy; k3 overwrites

    hipLaunchKernelGGL(k0_wt,       dim3(32),   dim3(256), 0, stream, W, Wt);
    hipLaunchKernelGGL(p1_prep,     dim3(512),  dim3(256), 0, stream, x, xtf, xth, xtl, sq);
    hipLaunchKernelGGL(k2_gram,     dim3(1024), dim3(256), 0, stream, xth, xtl, sq, candb);
    hipLaunchKernelGGL(k2b_rescore, dim3(8192), dim3(256), 0, stream, xtf, sq, candb, knn);
    hipLaunchKernelGGL(k1_prep,     dim3(256),  dim3(256), 0, stream, x, Wt, y1, y2);
    hipLaunchKernelGGL(k3_out,      dim3(512),  dim3(256), 0, stream, y1, y2, knn, bias, out);
}

// Round 4
// 376.875 us; speedup vs baseline: 3.6477x; 1.4235x over previous
//
#include <hip/hip_runtime.h>
#include <float.h>

typedef unsigned long long u64;
typedef unsigned int u32;
typedef unsigned short u16;

#define NPTS 4096
#define CDIM 64
#define BATCH 8
#define KSEL 20

// float-unit offsets in ws (~19.6 MB, same footprint as prior rounds)
#define OFF_Y1 0
#define OFF_XTL (BATCH * NPTS * CDIM / 2)       // xth [0,4MB), xtl [4,8MB)
#define OFF_Y2 (BATCH * NPTS * 64)              // [8,16MB): cand during k2/k2b, y2 after
#define OFF_SQ (2 * BATCH * NPTS * 64)
#define OFF_WT (OFF_SQ + BATCH * NPTS)
#define OFF_KNN (OFF_WT + 64 * 128)

typedef __attribute__((ext_vector_type(8))) short short8v;   // 8 bf16 (4 VGPR)
typedef __attribute__((ext_vector_type(16))) float float16v; // MFMA 32x32 acc

#define MFMA32(a, b, c) __builtin_amdgcn_mfma_f32_32x32x16_bf16(a, b, c, 0, 0, 0)

__device__ __forceinline__ u32 ordf(float f) {
    u32 u = __float_as_uint(f);
    return (u >> 31) ? ~u : (u | 0x80000000u);
}
__device__ __forceinline__ u32 umaxu(u32 a, u32 b) { return a > b ? a : b; }
__device__ __forceinline__ u32 uminu(u32 a, u32 b) { return a < b ? a : b; }

__device__ __forceinline__ void load_lds_16(const void* g, void* l) {
    __builtin_amdgcn_global_load_lds(
        (const __attribute__((address_space(1))) unsigned int*)g,
        (__attribute__((address_space(3))) unsigned int*)l, 16, 0, 0);
}

// in-register bitonic sort, 16 u32 keys, descending; all static indices
__device__ __forceinline__ void sort16_desc(u32 (&c)[16]) {
#pragma unroll
    for (int k = 2; k <= 16; k <<= 1)
#pragma unroll
        for (int j = k >> 1; j >= 1; j >>= 1)
#pragma unroll
            for (int i = 0; i < 16; i++)
                if ((i & j) == 0) {
                    int p = i | j;
                    bool up = ((i & k) == 0);
                    u32 a = c[i], b = c[p];
                    u32 mx = a > b ? a : b, mn = a > b ? b : a;
                    c[i] = up ? mx : mn;
                    c[p] = up ? mn : mx;
                }
}

// L (desc,32) <- top-32 of L ∪ c (desc,16): max-half + bitonic merge
__device__ __forceinline__ void merge_into(u32 (&L)[32], const u32 (&c)[16]) {
#pragma unroll
    for (int i = 16; i < 32; i++) L[i] = umaxu(L[i], c[31 - i]);
#pragma unroll
    for (int j = 16; j >= 1; j >>= 1)
#pragma unroll
        for (int i = 0; i < 32; i++)
            if ((i & j) == 0) {
                int p = i | j;
                u32 a = L[i], b = L[p];
                L[i] = umaxu(a, b);
                L[p] = uminu(a, b);
            }
}

// ---------------------------------------------------------------------------
// k0: W (64 x 128) -> Wt[c][o'] (64 x 128): o'<64: W1^T ; o'>=64: (W2-W1)^T
// ---------------------------------------------------------------------------
__global__ void k0_wt(const float* __restrict__ W, float* __restrict__ Wt) {
    int f = blockIdx.x * 256 + threadIdx.x;
    if (f >= 64 * 128) return;
    int c = f >> 7, o = f & 127;
    float v;
    if (o < 64) {
        v = W[o * 128 + c];
    } else {
        int oo = o - 64;
        v = W[oo * 128 + 64 + c] - W[oo * 128 + c];
    }
    Wt[f] = v;
}

// ---------------------------------------------------------------------------
// p1: transpose x[b][c][n] -> xtf (fp32, in d_out), xth/xtl (bf16 hi/lo, RNE),
// sq[n]. (validated rounds 2-3)
// ---------------------------------------------------------------------------
__global__ __launch_bounds__(256) void p1_prep(const float* __restrict__ x,
                                               float* __restrict__ xtf,
                                               u16* __restrict__ xth,
                                               u16* __restrict__ xtl,
                                               float* __restrict__ sq) {
    __shared__ float Xp[64][65];
    int tid = threadIdx.x;
    int b = blockIdx.x >> 6;
    int n0 = (blockIdx.x & 63) * 64;
    const float* xb = x + (size_t)b * (CDIM * NPTS);
    int j = tid & 63, cq = tid >> 6;
#pragma unroll
    for (int i = 0; i < 16; i++) {
        int c = cq * 16 + i;
        Xp[c][j] = xb[(size_t)c * NPTS + n0 + j];
    }
    __syncthreads();
    if (tid < 64) {
        float s = 0.f;
        for (int c = 0; c < 64; c++) { float v = Xp[c][tid]; s = fmaf(v, v, s); }
        sq[(size_t)b * NPTS + n0 + tid] = s;
    }
    int n = tid >> 2, c0 = (tid & 3) * 16;
    float vv[16];
#pragma unroll
    for (int i = 0; i < 16; i++) vv[i] = Xp[c0 + i][n];
    size_t rowb = ((size_t)b * NPTS + n0 + n) * 64 + c0;
#pragma unroll
    for (int q = 0; q < 4; q++) {
        float4 f;
        f.x = vv[4 * q]; f.y = vv[4 * q + 1]; f.z = vv[4 * q + 2]; f.w = vv[4 * q + 3];
        *(float4*)(xtf + rowb + 4 * q) = f;
    }
    u16 hb[16], lb[16];
#pragma unroll
    for (int i = 0; i < 16; i++) {
        float v = vv[i];
        u32 bv = __float_as_uint(v);
        u32 h = (bv + 0x7FFFu + ((bv >> 16) & 1u)) >> 16;    // RNE bf16
        float hf = __uint_as_float(h << 16);
        float lf = v - hf;
        u32 bl = __float_as_uint(lf);
        u32 lo = (bl + 0x7FFFu + ((bl >> 16) & 1u)) >> 16;
        hb[i] = (u16)h; lb[i] = (u16)lo;
    }
    uint4 H0, H1, L0, L1;
    H0.x = hb[0] | ((u32)hb[1] << 16);  H0.y = hb[2] | ((u32)hb[3] << 16);
    H0.z = hb[4] | ((u32)hb[5] << 16);  H0.w = hb[6] | ((u32)hb[7] << 16);
    H1.x = hb[8] | ((u32)hb[9] << 16);  H1.y = hb[10] | ((u32)hb[11] << 16);
    H1.z = hb[12] | ((u32)hb[13] << 16); H1.w = hb[14] | ((u32)hb[15] << 16);
    L0.x = lb[0] | ((u32)lb[1] << 16);  L0.y = lb[2] | ((u32)lb[3] << 16);
    L0.z = lb[4] | ((u32)lb[5] << 16);  L0.w = lb[6] | ((u32)lb[7] << 16);
    L1.x = lb[8] | ((u32)lb[9] << 16);  L1.y = lb[10] | ((u32)lb[11] << 16);
    L1.z = lb[12] | ((u32)lb[13] << 16); L1.w = lb[14] | ((u32)lb[15] << 16);
    *(uint4*)(xth + rowb) = H0;
    *(uint4*)(xth + rowb + 8) = H1;
    *(uint4*)(xtl + rowb) = L0;
    *(uint4*)(xtl + rowb + 8) = L1;
}

// ---------------------------------------------------------------------------
// k2: MFMA Gram (2-product: Ah*Bh + Al*Bh) over (128 rows x 1024-col chunk) +
// per-lane register top-32 via bitonic sort/merge -> cand cols (u16).
// Grid 1024 = 8 b x 32 rowtiles x 4 chunks; 256 thr (4 waves).
// B-tile (64 cols x 64 k, hi only, 8 KB) double-buffered via global_load_lds:
// linear LDS dest + inverse-XOR-swizzled global source (rule #21).
// ---------------------------------------------------------------------------
__device__ __forceinline__ void stage_tile(const u16* __restrict__ srcb,
                                           char* lds, int w, int lane) {
#pragma unroll
    for (int i = 0; i < 2; i++) {
        int G = w * 128 + i * 64 + lane;          // 16B granule index in [0,512)
        int rr = G >> 3, gp = G & 7;              // row (gram col), granule-in-row
        const u16* src = srcb + rr * 64 + ((gp ^ (rr & 7)) << 3);
        char* dst = lds + (w * 128 + i * 64) * 16;      // wave-uniform base
        load_lds_16(src, dst);                          // HW adds lane*16
    }
}

__global__ __launch_bounds__(256, 3) void k2_gram(const u16* __restrict__ xth,
                                                  const u16* __restrict__ xtl,
                                                  const float* __restrict__ sq,
                                                  u16* __restrict__ cand) {
    __shared__ char pool[2][8192];     // B-tile dbuf (hi only, XOR-swizzled)
    __shared__ float T[4][32][68];     // per-wave score transpose (34.8 KB)
    int tid = threadIdx.x;
    int lane = tid & 63, w = tid >> 6;
    int l31 = lane & 31, lh = lane >> 5;
    int b = blockIdx.x & 7;                 // batch == XCD slot -> L2 locality
    int rt = (blockIdx.x >> 3) & 31;
    int ch = blockIdx.x >> 8;
    int r0 = rt * 128;
    int cb = ch * 1024;
    size_t bbase = (size_t)b * NPTS;

    // A fragments: rows r0+32w..+31, K=64 in 4 k-steps (hi+lo, regs all run)
    short8v Ah[4], Al[4];
    {
        const u16* pa = xth + (bbase + r0 + 32 * w + l31) * 64 + 8 * lh;
        const u16* pl = xtl + (bbase + r0 + 32 * w + l31) * 64 + 8 * lh;
#pragma unroll
        for (int s = 0; s < 4; s++) {
            Ah[s] = *(const short8v*)(pa + 16 * s);
            Al[s] = *(const short8v*)(pl + 16 * s);
        }
    }

    u32 L[32];
#pragma unroll
    for (int i = 0; i < 32; i++) L[i] = 0u;

    stage_tile(xth + (bbase + cb) * 64, pool[0], w, lane);
    __syncthreads();

    float (*Tw)[68] = T[w];

    for (int t = 0; t < 16; t++) {
        int n1 = cb + t * 64;
        if (t < 15)
            stage_tile(xth + (bbase + n1 + 64) * 64, pool[(t + 1) & 1], w, lane);

        const char* pb = pool[t & 1];
        float16v a0 = {}, a1 = {};
#pragma unroll
        for (int s = 0; s < 4; s++) {
            int gx = 2 * s + lh;
            int sw = (gx ^ (l31 & 7)) << 4;
            short8v bh0 = *(const short8v*)(pb + l31 * 128 + sw);
            short8v bh1 = *(const short8v*)(pb + (32 + l31) * 128 + sw);
            a0 = MFMA32(Ah[s], bh0, a0);    // cols n1+0..31
            a0 = MFMA32(Al[s], bh0, a0);
            a1 = MFMA32(Ah[s], bh1, a1);    // cols n1+32..63
            a1 = MFMA32(Al[s], bh1, a1);
        }

        // transpose scores through per-wave LDS (2-way banks = free)
#pragma unroll
        for (int r = 0; r < 16; r++) {
            int row = (r & 3) + 8 * (r >> 2) + 4 * lh;   // m101 C/D row map
            Tw[row][l31] = a0[r];
            Tw[row][32 + l31] = a1[r];
        }

#pragma unroll
        for (int half = 0; half < 2; half++) {
            int col0 = 32 * half + 16 * lh;
            const float* sqp = sq + bbase + n1 + col0;
            u32 c[16];
#pragma unroll
            for (int q = 0; q < 4; q++) {
                float4 vv = *(const float4*)&Tw[l31][col0 + 4 * q];
                float4 sv = *(const float4*)(sqp + 4 * q);
                float s0 = fmaf(2.f, vv.x, -sv.x);
                float s1 = fmaf(2.f, vv.y, -sv.y);
                float s2 = fmaf(2.f, vv.z, -sv.z);
                float s3 = fmaf(2.f, vv.w, -sv.w);
                u32 cb2 = (u32)(n1 + col0 + 4 * q);
                c[4 * q + 0] = (ordf(s0) & 0xFFFF0000u) | (cb2 + 0);
                c[4 * q + 1] = (ordf(s1) & 0xFFFF0000u) | (cb2 + 1);
                c[4 * q + 2] = (ordf(s2) & 0xFFFF0000u) | (cb2 + 2);
                c[4 * q + 3] = (ordf(s3) & 0xFFFF0000u) | (cb2 + 3);
            }
            sort16_desc(c);
            merge_into(L, c);
        }
        __syncthreads();    // drains vmcnt (next buf ready) + frees cur buf
    }

    // merge the row's two lane-lists: top-32 of union = max(A_i, B_{31-i})
    u32 M[32];
#pragma unroll
    for (int i = 0; i < 32; i++) {
        u32 pv = __shfl_xor(L[31 - i], 32);
        M[i] = umaxu(L[i], pv);
    }
    if (lane < 32) {
        u16* cr = cand + (bbase + r0 + 32 * w + l31) * 128 + ch * 32;
#pragma unroll
        for (int q = 0; q < 16; q++) {
            u32 pk = (M[2 * q] & 0xFFFFu) | ((M[2 * q + 1] & 0xFFFFu) << 16);
            *(u32*)(cr + 2 * q) = pk;
        }
    }
}

// ---------------------------------------------------------------------------
// k2b: exact fp32 rescore of 128 candidates/row + distributed bitonic top-20.
// 8192 blocks x 256 thr; wave = one row. XCD-swizzled: XCD x <- batch x.
// ---------------------------------------------------------------------------
__global__ __launch_bounds__(256) void k2b_rescore(const float* __restrict__ xtf,
                                                   const float* __restrict__ sq,
                                                   const u16* __restrict__ cand,
                                                   int* __restrict__ knn) {
    __shared__ float xr[4][64];
    int tid = threadIdx.x;
    int lane = tid & 63, w = tid >> 6;
    int bid = blockIdx.x;
    size_t sb = (size_t)((bid & 7) * 1024 + (bid >> 3));   // bijective (8192%8==0)
    size_t row = sb * 4 + w;
    size_t bbase = (row >> 12) << 12;

    if (lane < 16)
        *(float4*)&xr[w][lane * 4] = *(const float4*)(xtf + row * 64 + lane * 4);
    __syncthreads();

    u32 cw = *(const u32*)(cand + row * 128 + 2 * lane);
    int m0 = (int)(cw & 0xFFFFu), m1 = (int)(cw >> 16);

    float d0 = 0.f, d1 = 0.f;
    const float* p0 = xtf + (bbase + m0) * 64;
    const float* p1 = xtf + (bbase + m1) * 64;
#pragma unroll
    for (int q = 0; q < 16; q++) {
        float4 xq = *(const float4*)&xr[w][4 * q];
        float4 v0 = *(const float4*)(p0 + 4 * q);
        float4 v1 = *(const float4*)(p1 + 4 * q);
        d0 = fmaf(v0.x, xq.x, d0); d0 = fmaf(v0.y, xq.y, d0);
        d0 = fmaf(v0.z, xq.z, d0); d0 = fmaf(v0.w, xq.w, d0);
        d1 = fmaf(v1.x, xq.x, d1); d1 = fmaf(v1.y, xq.y, d1);
        d1 = fmaf(v1.z, xq.z, d1); d1 = fmaf(v1.w, xq.w, d1);
    }
    float s0 = fmaf(2.f, d0, -sq[bbase + m0]);
    float s1 = fmaf(2.f, d1, -sq[bbase + m1]);
    u64 kA = ((u64)ordf(s0) << 32) | (u32)(~(u32)m0);
    u64 kB = ((u64)ordf(s1) << 32) | (u32)(~(u32)m1);

#pragma unroll
    for (u32 k = 2; k <= 64; k <<= 1) {
#pragma unroll
        for (u32 j2 = k >> 1; j2 >= 1; j2 >>= 1) {
            bool up = ((lane & k) == 0);
            bool lower = ((lane & j2) == 0);
            u64 pA = __shfl_xor(kA, j2);
            u64 mxA = (kA > pA) ? kA : pA, mnA = (kA > pA) ? pA : kA;
            kA = (lower == up) ? mxA : mnA;
            u64 pB = __shfl_xor(kB, j2);
            u64 mxB = (kB > pB) ? kB : pB, mnB = (kB > pB) ? pB : kB;
            kB = (lower == up) ? mxB : mnB;
        }
    }
    u64 rB = __shfl(kB, 63 - lane);
    u64 M = (kA > rB) ? kA : rB;
#pragma unroll
    for (u32 j2 = 32; j2 >= 1; j2 >>= 1) {
        u64 p = __shfl_xor(M, j2);
        bool lower = ((lane & j2) == 0);
        u64 mx = (M > p) ? M : p, mn = (M > p) ? p : M;
        M = lower ? mx : mn;
    }
    if (lane < KSEL)
        knn[row * KSEL + lane] = (int)(~(u32)M);
}

// ---------------------------------------------------------------------------
// k1: y1[n][o] = sum_c x[b][c][n]*Wt[c][o] (o'<64); y2: o'>=64. (validated)
// ---------------------------------------------------------------------------
__global__ __launch_bounds__(256) void k1_prep(const float* __restrict__ x,
                                               const float* __restrict__ Wtg,
                                               float* __restrict__ y1,
                                               float* __restrict__ y2) {
    __shared__ float Xt[64][128];
    __shared__ float Wt[64][128];
    int tid = threadIdx.x;
    int gr0 = blockIdx.x * 128;
    int b = gr0 >> 12;
    int n0 = gr0 & 4095;
    const float* xb = x + (size_t)b * (CDIM * NPTS) + n0;

    for (int k = 0; k < 32; k++) {
        int f = tid + 256 * k;
        int c = f >> 7, j = f & 127;
        Xt[c][j] = xb[(size_t)c * NPTS + j];
        ((float*)Wt)[f] = Wtg[f];
    }
    __syncthreads();

    int tr = tid & 15, tc = tid >> 4;
    float acc[8][8];
#pragma unroll
    for (int i = 0; i < 8; i++)
#pragma unroll
        for (int j = 0; j < 8; j++) acc[i][j] = 0.f;

#pragma unroll 4
    for (int c = 0; c < 64; c++) {
        float a[8], bb[8];
        *(float4*)&a[0]  = *(const float4*)&Xt[c][8 * tr];
        *(float4*)&a[4]  = *(const float4*)&Xt[c][8 * tr + 4];
        *(float4*)&bb[0] = *(const float4*)&Wt[c][8 * tc];
        *(float4*)&bb[4] = *(const float4*)&Wt[c][8 * tc + 4];
#pragma unroll
        for (int i = 0; i < 8; i++)
#pragma unroll
            for (int j = 0; j < 8; j++) acc[i][j] = fmaf(a[i], bb[j], acc[i][j]);
    }

#pragma unroll
    for (int i = 0; i < 8; i++) {
        int r = gr0 + 8 * tr + i;
        float* dst = (tc < 8) ? (y1 + (size_t)r * 64 + 8 * tc)
                              : (y2 + (size_t)r * 64 + (8 * tc - 64));
        float4 s0, s1;
        s0.x = acc[i][0]; s0.y = acc[i][1]; s0.z = acc[i][2]; s0.w = acc[i][3];
        s1.x = acc[i][4]; s1.y = acc[i][5]; s1.z = acc[i][6]; s1.w = acc[i][7];
        *(float4*)dst = s0;
        *(float4*)(dst + 4) = s1;
    }
}

// ---------------------------------------------------------------------------
// k3: out[b][o][n] = max_k y1[b][idx[n][k]][o] + y2[b][n][o] + bias[o]
// XCD-swizzled (batch = bid&7) so y1-gather stays in one XCD's L2.
// ---------------------------------------------------------------------------
__global__ __launch_bounds__(256) void k3_out(const float* __restrict__ y1,
                                              const float* __restrict__ y2,
                                              const int* __restrict__ knn,
                                              const float* __restrict__ bias,
                                              float* __restrict__ out) {
    __shared__ float outT[64][65];
    __shared__ int idxT[64 * KSEL];
    int tid = threadIdx.x;
    int b = blockIdx.x & 7;
    int n0 = ((blockIdx.x >> 3) & 63) * 64;

    for (int f = tid; f < 64 * KSEL; f += 256)
        idxT[f] = knn[((size_t)b * NPTS + n0) * KSEL + f];
    __syncthreads();

    int lane = tid & 63, w = tid >> 6;
    float bl = bias[lane];
    const float* y1b = y1 + (size_t)b * NPTS * 64;

    for (int i = 0; i < 16; i++) {
        int rr = w * 16 + i;
        float acc = -FLT_MAX;
#pragma unroll
        for (int k = 0; k < KSEL; k++) {
            int m = idxT[rr * KSEL + k];
            acc = fmaxf(acc, y1b[(size_t)m * 64 + lane]);
        }
        acc = acc + y2[((size_t)b * NPTS + n0 + rr) * 64 + lane] + bl;
        outT[lane][rr] = acc;
    }
    __syncthreads();

    int j = tid & 63, og = tid >> 6;
    for (int oo = 0; oo < 16; oo++) {
        int o = og * 16 + oo;
        out[((size_t)(b * 64 + o)) * NPTS + n0 + j] = outT[o][j];
    }
}

// ---------------------------------------------------------------------------
extern "C" void kernel_launch(void* const* d_in, const int* in_sizes, int n_in,
                              void* d_out, int out_size, void* d_ws, size_t ws_size,
                              hipStream_t stream) {
    const float* x    = (const float*)d_in[0];   // (8, 64, 4096)
    const float* W    = (const float*)d_in[1];   // (64, 128)
    const float* bias = (const float*)d_in[2];   // (64,)
    float* out = (float*)d_out;                  // (8, 64, 4096)
    float* ws = (float*)d_ws;

    u16* xth   = (u16*)ws;                  // [0,4MB)   dies before k1
    u16* xtl   = (u16*)(ws + OFF_XTL);      // [4,8MB)   dies before k1
    u16* candb = (u16*)(ws + OFF_Y2);       // [8,16MB)  dies before k1 writes y2
    float* y1  = ws + OFF_Y1;
    float* y2  = ws + OFF_Y2;
    float* sq  = ws + OFF_SQ;
    float* Wt  = ws + OFF_WT;
    int* knn   = (int*)(ws + OFF_KNN);
    float* xtf = (float*)d_out;             // fp32 transposed copy; k3 overwrites

    hipLaunchKernelGGL(k0_wt,       dim3(32),   dim3(256), 0, stream, W, Wt);
    hipLaunchKernelGGL(p1_prep,     dim3(512),  dim3(256), 0, stream, x, xtf, xth, xtl, sq);
    hipLaunchKernelGGL(k2_gram,     dim3(1024), dim3(256), 0, stream, xth, xtl, sq, candb);
    hipLaunchKernelGGL(k2b_rescore, dim3(8192), dim3(256), 0, stream, xtf, sq, candb, knn);
    hipLaunchKernelGGL(k1_prep,     dim3(256),  dim3(256), 0, stream, x, Wt, y1, y2);
    hipLaunchKernelGGL(k3_out,      dim3(512),  dim3(256), 0, stream, y1, y2, knn, bias, out);
}

// Round 5
// 210.356 us; speedup vs baseline: 6.5353x; 1.7916x over previous
//
#include <hip/hip_runtime.h>
#include <float.h>

typedef unsigned long long u64;
typedef unsigned int u32;
typedef unsigned short u16;

#define NPTS 4096
#define CDIM 64
#define BATCH 8
#define KSEL 20

// float-unit offsets in ws (~19.6 MB, same footprint as prior rounds)
#define OFF_Y1 0
#define OFF_XTL (BATCH * NPTS * CDIM / 2)       // xth [0,4MB), xtl [4,8MB)
#define OFF_Y2 (BATCH * NPTS * 64)              // [8,16MB): cand during k2/k2b, y2 after
#define OFF_SQ (2 * BATCH * NPTS * 64)
#define OFF_WT (OFF_SQ + BATCH * NPTS)
#define OFF_KNN (OFF_WT + 64 * 128)

typedef __attribute__((ext_vector_type(8))) short short8v;   // 8 bf16 (4 VGPR)
typedef __attribute__((ext_vector_type(16))) float float16v; // MFMA 32x32 acc

#define MFMA32(a, b, c) __builtin_amdgcn_mfma_f32_32x32x16_bf16(a, b, c, 0, 0, 0)

__device__ __forceinline__ u32 ordf(float f) {
    u32 u = __float_as_uint(f);
    return (u >> 31) ? ~u : (u | 0x80000000u);
}
__device__ __forceinline__ u32 umaxu(u32 a, u32 b) { return a > b ? a : b; }
__device__ __forceinline__ u32 uminu(u32 a, u32 b) { return a < b ? a : b; }

__device__ __forceinline__ void load_lds_16(const void* g, void* l) {
    __builtin_amdgcn_global_load_lds(
        (const __attribute__((address_space(1))) unsigned int*)g,
        (__attribute__((address_space(3))) unsigned int*)l, 16, 0, 0);
}

// in-register bitonic sort, 16 u32 keys, descending; all static indices
__device__ __forceinline__ void sort16_desc(u32 (&c)[16]) {
#pragma unroll
    for (int k = 2; k <= 16; k <<= 1)
#pragma unroll
        for (int j = k >> 1; j >= 1; j >>= 1)
#pragma unroll
            for (int i = 0; i < 16; i++)
                if ((i & j) == 0) {
                    int p = i | j;
                    bool up = ((i & k) == 0);
                    u32 a = c[i], b = c[p];
                    u32 mx = a > b ? a : b, mn = a > b ? b : a;
                    c[i] = up ? mx : mn;
                    c[p] = up ? mn : mx;
                }
}

// L (desc,16) <- top-16 of L ∪ c (desc,16): max-half + bitonic merge
__device__ __forceinline__ void merge_into16(u32 (&L)[16], const u32 (&c)[16]) {
#pragma unroll
    for (int i = 0; i < 16; i++) L[i] = umaxu(L[i], c[15 - i]);
#pragma unroll
    for (int j = 8; j >= 1; j >>= 1)
#pragma unroll
        for (int i = 0; i < 16; i++)
            if ((i & j) == 0) {
                int p = i | j;
                u32 a = L[i], b = L[p];
                L[i] = umaxu(a, b);
                L[p] = uminu(a, b);
            }
}

// ---------------------------------------------------------------------------
// k0: W (64 x 128) -> Wt[c][o'] (64 x 128): o'<64: W1^T ; o'>=64: (W2-W1)^T
// ---------------------------------------------------------------------------
__global__ void k0_wt(const float* __restrict__ W, float* __restrict__ Wt) {
    int f = blockIdx.x * 256 + threadIdx.x;
    if (f >= 64 * 128) return;
    int c = f >> 7, o = f & 127;
    float v;
    if (o < 64) {
        v = W[o * 128 + c];
    } else {
        int oo = o - 64;
        v = W[oo * 128 + 64 + c] - W[oo * 128 + c];
    }
    Wt[f] = v;
}

// ---------------------------------------------------------------------------
// p1: transpose x[b][c][n] -> xtf (fp32, in d_out), xth/xtl (bf16 hi/lo, RNE),
// sq[n]. (validated rounds 2-4)
// ---------------------------------------------------------------------------
__global__ __launch_bounds__(256) void p1_prep(const float* __restrict__ x,
                                               float* __restrict__ xtf,
                                               u16* __restrict__ xth,
                                               u16* __restrict__ xtl,
                                               float* __restrict__ sq) {
    __shared__ float Xp[64][65];
    int tid = threadIdx.x;
    int b = blockIdx.x >> 6;
    int n0 = (blockIdx.x & 63) * 64;
    const float* xb = x + (size_t)b * (CDIM * NPTS);
    int j = tid & 63, cq = tid >> 6;
#pragma unroll
    for (int i = 0; i < 16; i++) {
        int c = cq * 16 + i;
        Xp[c][j] = xb[(size_t)c * NPTS + n0 + j];
    }
    __syncthreads();
    if (tid < 64) {
        float s = 0.f;
        for (int c = 0; c < 64; c++) { float v = Xp[c][tid]; s = fmaf(v, v, s); }
        sq[(size_t)b * NPTS + n0 + tid] = s;
    }
    int n = tid >> 2, c0 = (tid & 3) * 16;
    float vv[16];
#pragma unroll
    for (int i = 0; i < 16; i++) vv[i] = Xp[c0 + i][n];
    size_t rowb = ((size_t)b * NPTS + n0 + n) * 64 + c0;
#pragma unroll
    for (int q = 0; q < 4; q++) {
        float4 f;
        f.x = vv[4 * q]; f.y = vv[4 * q + 1]; f.z = vv[4 * q + 2]; f.w = vv[4 * q + 3];
        *(float4*)(xtf + rowb + 4 * q) = f;
    }
    u16 hb[16], lb[16];
#pragma unroll
    for (int i = 0; i < 16; i++) {
        float v = vv[i];
        u32 bv = __float_as_uint(v);
        u32 h = (bv + 0x7FFFu + ((bv >> 16) & 1u)) >> 16;    // RNE bf16
        float hf = __uint_as_float(h << 16);
        float lf = v - hf;
        u32 bl = __float_as_uint(lf);
        u32 lo = (bl + 0x7FFFu + ((bl >> 16) & 1u)) >> 16;
        hb[i] = (u16)h; lb[i] = (u16)lo;
    }
    uint4 H0, H1, L0, L1;
    H0.x = hb[0] | ((u32)hb[1] << 16);  H0.y = hb[2] | ((u32)hb[3] << 16);
    H0.z = hb[4] | ((u32)hb[5] << 16);  H0.w = hb[6] | ((u32)hb[7] << 16);
    H1.x = hb[8] | ((u32)hb[9] << 16);  H1.y = hb[10] | ((u32)hb[11] << 16);
    H1.z = hb[12] | ((u32)hb[13] << 16); H1.w = hb[14] | ((u32)hb[15] << 16);
    L0.x = lb[0] | ((u32)lb[1] << 16);  L0.y = lb[2] | ((u32)lb[3] << 16);
    L0.z = lb[4] | ((u32)lb[5] << 16);  L0.w = lb[6] | ((u32)lb[7] << 16);
    L1.x = lb[8] | ((u32)lb[9] << 16);  L1.y = lb[10] | ((u32)lb[11] << 16);
    L1.z = lb[12] | ((u32)lb[13] << 16); L1.w = lb[14] | ((u32)lb[15] << 16);
    *(uint4*)(xth + rowb) = H0;
    *(uint4*)(xth + rowb + 8) = H1;
    *(uint4*)(xtl + rowb) = L0;
    *(uint4*)(xtl + rowb + 8) = L1;
}

// ---------------------------------------------------------------------------
// k2: MFMA Gram (2-product: Ah*Bh + Al*Bh) over (128 rows x 1024-col chunk) +
// per-lane register top-16 per col-class (2 classes = bit4 of col) -> cand.
// Grid 1024 = 8 b x 32 rowtiles x 4 chunks; 256 thr (4 waves); 4 blocks/CU.
// B-tile (64 cols x 64 k, hi only, 8 KB) double-buffered via global_load_lds.
// ---------------------------------------------------------------------------
__device__ __forceinline__ void stage_tile(const u16* __restrict__ srcb,
                                           char* lds, int w, int lane) {
#pragma unroll
    for (int i = 0; i < 2; i++) {
        int G = w * 128 + i * 64 + lane;          // 16B granule index in [0,512)
        int rr = G >> 3, gp = G & 7;              // row (gram col), granule-in-row
        const u16* src = srcb + rr * 64 + ((gp ^ (rr & 7)) << 3);
        char* dst = lds + (w * 128 + i * 64) * 16;      // wave-uniform base
        load_lds_16(src, dst);                          // HW adds lane*16
    }
}

// score/select one 32-col acc: write scores to Tw, read 16 cols (class = lh),
// build quantized keys, sort + merge into per-lane top-16.
__device__ __forceinline__ void sel_phase(const float16v& A, float (*Tw)[36],
                                          const float* __restrict__ sqp,
                                          int colg, int l31, int lh,
                                          u32 (&L)[16]) {
#pragma unroll
    for (int r = 0; r < 16; r++) {
        int row = (r & 3) + 8 * (r >> 2) + 4 * lh;   // m101 C/D row map
        Tw[row][l31] = A[r];
    }
    // same-wave LDS RAW: compiler inserts lgkmcnt waits (validated r3/r4)
    u32 c[16];
#pragma unroll
    for (int q = 0; q < 4; q++) {
        float4 vv = *(const float4*)&Tw[l31][16 * lh + 4 * q];
        float4 sv = *(const float4*)(sqp + 4 * q);
        float s0 = fmaf(2.f, vv.x, -sv.x);
        float s1 = fmaf(2.f, vv.y, -sv.y);
        float s2 = fmaf(2.f, vv.z, -sv.z);
        float s3 = fmaf(2.f, vv.w, -sv.w);
        u32 cb2 = (u32)(colg + 4 * q);
        c[4 * q + 0] = (ordf(s0) & 0xFFFF0000u) | (cb2 + 0);
        c[4 * q + 1] = (ordf(s1) & 0xFFFF0000u) | (cb2 + 1);
        c[4 * q + 2] = (ordf(s2) & 0xFFFF0000u) | (cb2 + 2);
        c[4 * q + 3] = (ordf(s3) & 0xFFFF0000u) | (cb2 + 3);
    }
    sort16_desc(c);
    merge_into16(L, c);
}

__global__ __launch_bounds__(256, 4) void k2_gram(const u16* __restrict__ xth,
                                                  const u16* __restrict__ xtl,
                                                  const float* __restrict__ sq,
                                                  u16* __restrict__ cand) {
    __shared__ char pool[2][8192];     // B-tile dbuf (hi only, XOR-swizzled)
    __shared__ float T[4][32][36];     // per-wave score transpose (18.4 KB)
    int tid = threadIdx.x;
    int lane = tid & 63, w = tid >> 6;
    int l31 = lane & 31, lh = lane >> 5;
    int b = blockIdx.x & 7;                 // batch == XCD slot -> L2 locality
    int rt = (blockIdx.x >> 3) & 31;
    int ch = blockIdx.x >> 8;
    int r0 = rt * 128;
    int cb = ch * 1024;
    size_t bbase = (size_t)b * NPTS;

    // A fragments: rows r0+32w..+31, K=64 in 4 k-steps (hi+lo, regs all run)
    short8v Ah[4], Al[4];
    {
        const u16* pa = xth + (bbase + r0 + 32 * w + l31) * 64 + 8 * lh;
        const u16* pl = xtl + (bbase + r0 + 32 * w + l31) * 64 + 8 * lh;
#pragma unroll
        for (int s = 0; s < 4; s++) {
            Ah[s] = *(const short8v*)(pa + 16 * s);
            Al[s] = *(const short8v*)(pl + 16 * s);
        }
    }

    u32 L[16];
#pragma unroll
    for (int i = 0; i < 16; i++) L[i] = 0u;

    stage_tile(xth + (bbase + cb) * 64, pool[0], w, lane);
    __syncthreads();

    float (*Tw)[36] = T[w];

    for (int t = 0; t < 16; t++) {
        int n1 = cb + t * 64;
        if (t < 15)
            stage_tile(xth + (bbase + n1 + 64) * 64, pool[(t + 1) & 1], w, lane);

        const char* pb = pool[t & 1];
        float16v a0 = {}, a1 = {};
#pragma unroll
        for (int s = 0; s < 4; s++) {
            int gx = 2 * s + lh;
            int sw = (gx ^ (l31 & 7)) << 4;
            short8v bh0 = *(const short8v*)(pb + l31 * 128 + sw);
            short8v bh1 = *(const short8v*)(pb + (32 + l31) * 128 + sw);
            a0 = MFMA32(Ah[s], bh0, a0);    // cols n1+0..31
            a0 = MFMA32(Al[s], bh0, a0);
            a1 = MFMA32(Ah[s], bh1, a1);    // cols n1+32..63
            a1 = MFMA32(Al[s], bh1, a1);
        }

        sel_phase(a0, Tw, sq + bbase + n1 + 16 * lh,      n1 + 16 * lh,      l31, lh, L);
        sel_phase(a1, Tw, sq + bbase + n1 + 32 + 16 * lh, n1 + 32 + 16 * lh, l31, lh, L);

        __syncthreads();    // drains vmcnt (next buf ready) + frees cur buf
    }

    // each lane writes its class-16 list verbatim: [ch*32 + 16*lh, +16)
    {
        u16* cr = cand + (bbase + r0 + 32 * w + l31) * 128 + ch * 32 + 16 * lh;
#pragma unroll
        for (int q = 0; q < 8; q++) {
            u32 pk = (L[2 * q] & 0xFFFFu) | ((L[2 * q + 1] & 0xFFFFu) << 16);
            *(u32*)(cr + 2 * q) = pk;
        }
    }
}

// ---------------------------------------------------------------------------
// k2b: exact fp32 rescore of 128 candidates/row + distributed bitonic top-20.
// 8192 blocks x 256 thr; wave = one row. Cooperative gather: 4 lanes per
// candidate, each instruction reads 16 full 64B lines (transaction-optimal).
// ---------------------------------------------------------------------------
__global__ __launch_bounds__(256) void k2b_rescore(const float* __restrict__ xtf,
                                                   const float* __restrict__ sq,
                                                   const u16* __restrict__ cand,
                                                   int* __restrict__ knn) {
    __shared__ float xr[4][64];
    __shared__ u32 cdw[4][64];      // 128 candidate ids (u16 packed)
    __shared__ float dd[4][128];    // raw dot products
    int tid = threadIdx.x;
    int lane = tid & 63, w = tid >> 6;
    int bid = blockIdx.x;
    size_t sb = (size_t)((bid & 7) * 1024 + (bid >> 3));   // batch = XCD slot
    size_t row = sb * 4 + w;
    size_t bbase = (row >> 12) << 12;

    if (lane < 16)
        *(float4*)&xr[w][lane * 4] = *(const float4*)(xtf + row * 64 + lane * 4);
    cdw[w][lane] = ((const u32*)cand)[row * 64 + lane];
    __syncthreads();

    int s = lane & 3, g = lane >> 2;
    const u16* cd16 = (const u16*)&cdw[w][0];

    // lane s covers floats {16q + 4s .. +4) of each candidate row (line q)
    float4 xq[4];
#pragma unroll
    for (int q = 0; q < 4; q++) xq[q] = *(const float4*)&xr[w][16 * q + 4 * s];

    int mm[8];
#pragma unroll
    for (int p = 0; p < 8; p++) mm[p] = cd16[p * 16 + g];

#pragma unroll
    for (int p = 0; p < 8; p++) {
        const float* pm = xtf + (bbase + mm[p]) * 64;
        float d = 0.f;
#pragma unroll
        for (int q = 0; q < 4; q++) {
            float4 v = *(const float4*)(pm + 16 * q + 4 * s);
            d = fmaf(v.x, xq[q].x, d); d = fmaf(v.y, xq[q].y, d);
            d = fmaf(v.z, xq[q].z, d); d = fmaf(v.w, xq[q].w, d);
        }
        d += __shfl_xor(d, 1);
        d += __shfl_xor(d, 2);
        if (s == 0) dd[w][p * 16 + g] = d;
    }

    // exact keys (fp32 score + lowest-index tie-break), 2 per lane
    float dA = dd[w][lane], dB = dd[w][64 + lane];
    int mA = cd16[lane], mB = cd16[64 + lane];
    float sA = fmaf(2.f, dA, -sq[bbase + mA]);
    float sB = fmaf(2.f, dB, -sq[bbase + mB]);
    u64 kA = ((u64)ordf(sA) << 32) | (u32)(~(u32)mA);
    u64 kB = ((u64)ordf(sB) << 32) | (u32)(~(u32)mB);

#pragma unroll
    for (u32 k = 2; k <= 64; k <<= 1) {
#pragma unroll
        for (u32 j2 = k >> 1; j2 >= 1; j2 >>= 1) {
            bool up = ((lane & k) == 0);
            bool lower = ((lane & j2) == 0);
            u64 pA = __shfl_xor(kA, j2);
            u64 mxA = (kA > pA) ? kA : pA, mnA = (kA > pA) ? pA : kA;
            kA = (lower == up) ? mxA : mnA;
            u64 pB = __shfl_xor(kB, j2);
            u64 mxB = (kB > pB) ? kB : pB, mnB = (kB > pB) ? pB : kB;
            kB = (lower == up) ? mxB : mnB;
        }
    }
    u64 rB = __shfl(kB, 63 - lane);
    u64 M = (kA > rB) ? kA : rB;
#pragma unroll
    for (u32 j2 = 32; j2 >= 1; j2 >>= 1) {
        u64 p = __shfl_xor(M, j2);
        bool lower = ((lane & j2) == 0);
        u64 mx = (M > p) ? M : p, mn = (M > p) ? p : M;
        M = lower ? mx : mn;
    }
    if (lane < KSEL)
        knn[row * KSEL + lane] = (int)(~(u32)M);
}

// ---------------------------------------------------------------------------
// k1: y1[n][o] = sum_c x[b][c][n]*Wt[c][o] (o'<64); y2: o'>=64. (validated)
// ---------------------------------------------------------------------------
__global__ __launch_bounds__(256) void k1_prep(const float* __restrict__ x,
                                               const float* __restrict__ Wtg,
                                               float* __restrict__ y1,
                                               float* __restrict__ y2) {
    __shared__ float Xt[64][128];
    __shared__ float Wt[64][128];
    int tid = threadIdx.x;
    int gr0 = blockIdx.x * 128;
    int b = gr0 >> 12;
    int n0 = gr0 & 4095;
    const float* xb = x + (size_t)b * (CDIM * NPTS) + n0;

    for (int k = 0; k < 32; k++) {
        int f = tid + 256 * k;
        int c = f >> 7, j = f & 127;
        Xt[c][j] = xb[(size_t)c * NPTS + j];
        ((float*)Wt)[f] = Wtg[f];
    }
    __syncthreads();

    int tr = tid & 15, tc = tid >> 4;
    float acc[8][8];
#pragma unroll
    for (int i = 0; i < 8; i++)
#pragma unroll
        for (int j = 0; j < 8; j++) acc[i][j] = 0.f;

#pragma unroll 4
    for (int c = 0; c < 64; c++) {
        float a[8], bb[8];
        *(float4*)&a[0]  = *(const float4*)&Xt[c][8 * tr];
        *(float4*)&a[4]  = *(const float4*)&Xt[c][8 * tr + 4];
        *(float4*)&bb[0] = *(const float4*)&Wt[c][8 * tc];
        *(float4*)&bb[4] = *(const float4*)&Wt[c][8 * tc + 4];
#pragma unroll
        for (int i = 0; i < 8; i++)
#pragma unroll
            for (int j = 0; j < 8; j++) acc[i][j] = fmaf(a[i], bb[j], acc[i][j]);
    }

#pragma unroll
    for (int i = 0; i < 8; i++) {
        int r = gr0 + 8 * tr + i;
        float* dst = (tc < 8) ? (y1 + (size_t)r * 64 + 8 * tc)
                              : (y2 + (size_t)r * 64 + (8 * tc - 64));
        float4 s0, s1;
        s0.x = acc[i][0]; s0.y = acc[i][1]; s0.z = acc[i][2]; s0.w = acc[i][3];
        s1.x = acc[i][4]; s1.y = acc[i][5]; s1.z = acc[i][6]; s1.w = acc[i][7];
        *(float4*)dst = s0;
        *(float4*)(dst + 4) = s1;
    }
}

// ---------------------------------------------------------------------------
// k3: out[b][o][n] = max_k y1[b][idx[n][k]][o] + y2[b][n][o] + bias[o]
// XCD-swizzled (batch = bid&7) so y1-gather stays in one XCD's L2.
// ---------------------------------------------------------------------------
__global__ __launch_bounds__(256) void k3_out(const float* __restrict__ y1,
                                              const float* __restrict__ y2,
                                              const int* __restrict__ knn,
                                              const float* __restrict__ bias,
                                              float* __restrict__ out) {
    __shared__ float outT[64][65];
    __shared__ int idxT[64 * KSEL];
    int tid = threadIdx.x;
    int b = blockIdx.x & 7;
    int n0 = ((blockIdx.x >> 3) & 63) * 64;

    for (int f = tid; f < 64 * KSEL; f += 256)
        idxT[f] = knn[((size_t)b * NPTS + n0) * KSEL + f];
    __syncthreads();

    int lane = tid & 63, w = tid >> 6;
    float bl = bias[lane];
    const float* y1b = y1 + (size_t)b * NPTS * 64;

    for (int i = 0; i < 16; i++) {
        int rr = w * 16 + i;
        float acc = -FLT_MAX;
#pragma unroll
        for (int k = 0; k < KSEL; k++) {
            int m = idxT[rr * KSEL + k];
            acc = fmaxf(acc, y1b[(size_t)m * 64 + lane]);
        }
        acc = acc + y2[((size_t)b * NPTS + n0 + rr) * 64 + lane] + bl;
        outT[lane][rr] = acc;
    }
    __syncthreads();

    int j = tid & 63, og = tid >> 6;
    for (int oo = 0; oo < 16; oo++) {
        int o = og * 16 + oo;
        out[((size_t)(b * 64 + o)) * NPTS + n0 + j] = outT[o][j];
    }
}

// ---------------------------------------------------------------------------
extern "C" void kernel_launch(void* const* d_in, const int* in_sizes, int n_in,
                              void* d_out, int out_size, void* d_ws, size_t ws_size,
                              hipStream_t stream) {
    const float* x    = (const float*)d_in[0];   // (8, 64, 4096)
    const float* W    = (const float*)d_in[1];   // (64, 128)
    const float* bias = (const float*)d_in[2];   // (64,)
    float* out = (float*)d_out;                  // (8, 64, 4096)
    float* ws = (float*)d_ws;

    u16* xth   = (u16*)ws;                  // [0,4MB)   dies before k1
    u16* xtl   = (u16*)(ws + OFF_XTL);      // [4,8MB)   dies before k1
    u16* candb = (u16*)(ws + OFF_Y2);       // [8,16MB)  dies before k1 writes y2
    float* y1  = ws + OFF_Y1;
    float* y2  = ws + OFF_Y2;
    float* sq  = ws + OFF_SQ;
    float* Wt  = ws + OFF_WT;
    int* knn   = (int*)(ws + OFF_KNN);
    float* xtf = (float*)d_out;             // fp32 transposed copy; k3 overwrites

    hipLaunchKernelGGL(k0_wt,       dim3(32),   dim3(256), 0, stream, W, Wt);
    hipLaunchKernelGGL(p1_prep,     dim3(512),  dim3(256), 0, stream, x, xtf, xth, xtl, sq);
    hipLaunchKernelGGL(k2_gram,     dim3(1024), dim3(256), 0, stream, xth, xtl, sq, candb);
    hipLaunchKernelGGL(k2b_rescore, dim3(8192), dim3(256), 0, stream, xtf, sq, candb, knn);
    hipLaunchKernelGGL(k1_prep,     dim3(256),  dim3(256), 0, stream, x, Wt, y1, y2);
    hipLaunchKernelGGL(k3_out,      dim3(512),  dim3(256), 0, stream, y1, y2, knn, bias, out);
}

// Round 6
// 203.705 us; speedup vs baseline: 6.7487x; 1.0327x over previous
//
#include <hip/hip_runtime.h>
#include <float.h>

typedef unsigned long long u64;
typedef unsigned int u32;
typedef unsigned short u16;

#define NPTS 4096
#define CDIM 64
#define BATCH 8
#define KSEL 20

// float-unit offsets in ws (~19.6 MB, same footprint as prior rounds)
#define OFF_Y1 0
#define OFF_XTL (BATCH * NPTS * CDIM / 2)       // xth [0,4MB), xtl [4,8MB)
#define OFF_Y2 (BATCH * NPTS * 64)              // [8,16MB): cand during k2/k2b, y2 after
#define OFF_SQ (2 * BATCH * NPTS * 64)
#define OFF_WT (OFF_SQ + BATCH * NPTS)
#define OFF_KNN (OFF_WT + 64 * 128)

typedef __attribute__((ext_vector_type(8))) short short8v;   // 8 bf16 (4 VGPR)
typedef __attribute__((ext_vector_type(16))) float float16v; // MFMA 32x32 acc

#define MFMA32(a, b, c) __builtin_amdgcn_mfma_f32_32x32x16_bf16(a, b, c, 0, 0, 0)

__device__ __forceinline__ u32 ordf(float f) {
    u32 u = __float_as_uint(f);
    return (u >> 31) ? ~u : (u | 0x80000000u);
}
__device__ __forceinline__ u32 umaxu(u32 a, u32 b) { return a > b ? a : b; }
__device__ __forceinline__ u32 uminu(u32 a, u32 b) { return a < b ? a : b; }

__device__ __forceinline__ void load_lds_16(const void* g, void* l) {
    __builtin_amdgcn_global_load_lds(
        (const __attribute__((address_space(1))) unsigned int*)g,
        (__attribute__((address_space(3))) unsigned int*)l, 16, 0, 0);
}

// in-register bitonic sort, 16 u32 keys, descending; all static indices
__device__ __forceinline__ void sort16_desc(u32 (&c)[16]) {
#pragma unroll
    for (int k = 2; k <= 16; k <<= 1)
#pragma unroll
        for (int j = k >> 1; j >= 1; j >>= 1)
#pragma unroll
            for (int i = 0; i < 16; i++)
                if ((i & j) == 0) {
                    int p = i | j;
                    bool up = ((i & k) == 0);
                    u32 a = c[i], b = c[p];
                    u32 mx = a > b ? a : b, mn = a > b ? b : a;
                    c[i] = up ? mx : mn;
                    c[p] = up ? mn : mx;
                }
}

// L (desc,16) <- top-16 of L ∪ c (desc,16): max-half + bitonic merge
__device__ __forceinline__ void merge_into16(u32 (&L)[16], const u32 (&c)[16]) {
#pragma unroll
    for (int i = 0; i < 16; i++) L[i] = umaxu(L[i], c[15 - i]);
#pragma unroll
    for (int j = 8; j >= 1; j >>= 1)
#pragma unroll
        for (int i = 0; i < 16; i++)
            if ((i & j) == 0) {
                int p = i | j;
                u32 a = L[i], b = L[p];
                L[i] = umaxu(a, b);
                L[p] = uminu(a, b);
            }
}

// ---------------------------------------------------------------------------
// k0: W (64 x 128) -> Wt[c][o'] (64 x 128): o'<64: W1^T ; o'>=64: (W2-W1)^T
// ---------------------------------------------------------------------------
__global__ void k0_wt(const float* __restrict__ W, float* __restrict__ Wt) {
    int f = blockIdx.x * 256 + threadIdx.x;
    if (f >= 64 * 128) return;
    int c = f >> 7, o = f & 127;
    float v;
    if (o < 64) {
        v = W[o * 128 + c];
    } else {
        int oo = o - 64;
        v = W[oo * 128 + 64 + c] - W[oo * 128 + c];
    }
    Wt[f] = v;
}

// ---------------------------------------------------------------------------
// p1: transpose x[b][c][n] -> xtf (fp32, in d_out), xth/xtl (bf16 hi/lo, RNE),
// sq[n]. (validated rounds 2-5)
// ---------------------------------------------------------------------------
__global__ __launch_bounds__(256) void p1_prep(const float* __restrict__ x,
                                               float* __restrict__ xtf,
                                               u16* __restrict__ xth,
                                               u16* __restrict__ xtl,
                                               float* __restrict__ sq) {
    __shared__ float Xp[64][65];
    int tid = threadIdx.x;
    int b = blockIdx.x >> 6;
    int n0 = (blockIdx.x & 63) * 64;
    const float* xb = x + (size_t)b * (CDIM * NPTS);
    int j = tid & 63, cq = tid >> 6;
#pragma unroll
    for (int i = 0; i < 16; i++) {
        int c = cq * 16 + i;
        Xp[c][j] = xb[(size_t)c * NPTS + n0 + j];
    }
    __syncthreads();
    if (tid < 64) {
        float s = 0.f;
        for (int c = 0; c < 64; c++) { float v = Xp[c][tid]; s = fmaf(v, v, s); }
        sq[(size_t)b * NPTS + n0 + tid] = s;
    }
    int n = tid >> 2, c0 = (tid & 3) * 16;
    float vv[16];
#pragma unroll
    for (int i = 0; i < 16; i++) vv[i] = Xp[c0 + i][n];
    size_t rowb = ((size_t)b * NPTS + n0 + n) * 64 + c0;
#pragma unroll
    for (int q = 0; q < 4; q++) {
        float4 f;
        f.x = vv[4 * q]; f.y = vv[4 * q + 1]; f.z = vv[4 * q + 2]; f.w = vv[4 * q + 3];
        *(float4*)(xtf + rowb + 4 * q) = f;
    }
    u16 hb[16], lb[16];
#pragma unroll
    for (int i = 0; i < 16; i++) {
        float v = vv[i];
        u32 bv = __float_as_uint(v);
        u32 h = (bv + 0x7FFFu + ((bv >> 16) & 1u)) >> 16;    // RNE bf16
        float hf = __uint_as_float(h << 16);
        float lf = v - hf;
        u32 bl = __float_as_uint(lf);
        u32 lo = (bl + 0x7FFFu + ((bl >> 16) & 1u)) >> 16;
        hb[i] = (u16)h; lb[i] = (u16)lo;
    }
    uint4 H0, H1, L0, L1;
    H0.x = hb[0] | ((u32)hb[1] << 16);  H0.y = hb[2] | ((u32)hb[3] << 16);
    H0.z = hb[4] | ((u32)hb[5] << 16);  H0.w = hb[6] | ((u32)hb[7] << 16);
    H1.x = hb[8] | ((u32)hb[9] << 16);  H1.y = hb[10] | ((u32)hb[11] << 16);
    H1.z = hb[12] | ((u32)hb[13] << 16); H1.w = hb[14] | ((u32)hb[15] << 16);
    L0.x = lb[0] | ((u32)lb[1] << 16);  L0.y = lb[2] | ((u32)lb[3] << 16);
    L0.z = lb[4] | ((u32)lb[5] << 16);  L0.w = lb[6] | ((u32)lb[7] << 16);
    L1.x = lb[8] | ((u32)lb[9] << 16);  L1.y = lb[10] | ((u32)lb[11] << 16);
    L1.z = lb[12] | ((u32)lb[13] << 16); L1.w = lb[14] | ((u32)lb[15] << 16);
    *(uint4*)(xth + rowb) = H0;
    *(uint4*)(xth + rowb + 8) = H1;
    *(uint4*)(xtl + rowb) = L0;
    *(uint4*)(xtl + rowb + 8) = L1;
}

// ---------------------------------------------------------------------------
// k2: MFMA Gram (2-product: Ah*Bh + Al*Bh) over (128 rows x 1024-col chunk) +
// per-lane register top-16 per col-class (2 classes = bit4 of col) -> cand.
// Grid 1024 = 8 b x 32 rowtiles x 4 chunks; 256 thr (4 waves); 5 blocks/CU.
// Single 8 KB B-tile buffer; stage(t+1) issued before sel(a1) so the async
// global_load_lds latency hides under ~400 cyc of selection VALU work.
// Keys: biased score s+1024 > 0 -> float bits monotone as uint; 20-bit score
// prefix | 12-bit col. Bias+2g+(-sq) folded into ONE fmaf at T-write (per-lane
// col is uniform across acc regs: m74 col=lane&31).
// ---------------------------------------------------------------------------
__device__ __forceinline__ void stage_tile(const u16* __restrict__ srcb,
                                           char* lds, int w, int lane) {
#pragma unroll
    for (int i = 0; i < 2; i++) {
        int G = w * 128 + i * 64 + lane;          // 16B granule index in [0,512)
        int rr = G >> 3, gp = G & 7;              // row (gram col), granule-in-row
        const u16* src = srcb + rr * 64 + ((gp ^ (rr & 7)) << 3);
        char* dst = lds + (w * 128 + i * 64) * 16;      // wave-uniform base
        load_lds_16(src, dst);                          // HW adds lane*16
    }
}

// score/select one 32-col acc: write biased scores to Tw, read 16 cols
// (class = lh), mask+tag keys, sort + merge into per-lane top-16.
__device__ __forceinline__ void sel_phase(const float16v& A, float (*Tw)[36],
                                          float pb, int colbase,
                                          int l31, int lh, u32 (&L)[16]) {
#pragma unroll
    for (int r = 0; r < 16; r++) {
        int row = (r & 3) + 8 * (r >> 2) + 4 * lh;   // m101 C/D row map
        Tw[row][l31] = fmaf(2.f, A[r], pb);          // s + 1024, always > 0
    }
    // same-wave LDS RAW: compiler inserts lgkmcnt waits (validated r3-r5)
    u32 c[16];
    const u32* Tu = (const u32*)&Tw[l31][16 * lh];
#pragma unroll
    for (int q = 0; q < 4; q++) {
        uint4 v = *(const uint4*)(Tu + 4 * q);
        u32 cg = (u32)(colbase + 16 * lh + 4 * q);
        c[4 * q + 0] = (v.x & 0xFFFFF000u) | (cg + 0);
        c[4 * q + 1] = (v.y & 0xFFFFF000u) | (cg + 1);
        c[4 * q + 2] = (v.z & 0xFFFFF000u) | (cg + 2);
        c[4 * q + 3] = (v.w & 0xFFFFF000u) | (cg + 3);
    }
    sort16_desc(c);
    merge_into16(L, c);
}

__global__ __launch_bounds__(256, 5) void k2_gram(const u16* __restrict__ xth,
                                                  const u16* __restrict__ xtl,
                                                  const float* __restrict__ sq,
                                                  u16* __restrict__ cand) {
    __shared__ char pool[8192];        // B-tile (hi only, XOR-swizzled)
    __shared__ float T[4][32][36];     // per-wave score transpose (18.4 KB)
    int tid = threadIdx.x;
    int lane = tid & 63, w = tid >> 6;
    int l31 = lane & 31, lh = lane >> 5;
    int b = blockIdx.x & 7;                 // batch == XCD slot -> L2 locality
    int rt = (blockIdx.x >> 3) & 31;
    int ch = blockIdx.x >> 8;
    int r0 = rt * 128;
    int cb = ch * 1024;
    size_t bbase = (size_t)b * NPTS;

    // A fragments: rows r0+32w..+31, K=64 in 4 k-steps (hi+lo, regs all run)
    short8v Ah[4], Al[4];
    {
        const u16* pa = xth + (bbase + r0 + 32 * w + l31) * 64 + 8 * lh;
        const u16* pl = xtl + (bbase + r0 + 32 * w + l31) * 64 + 8 * lh;
#pragma unroll
        for (int s = 0; s < 4; s++) {
            Ah[s] = *(const short8v*)(pa + 16 * s);
            Al[s] = *(const short8v*)(pl + 16 * s);
        }
    }

    u32 L[16];
#pragma unroll
    for (int i = 0; i < 16; i++) L[i] = 0u;

    stage_tile(xth + (bbase + cb) * 64, pool, w, lane);
    __syncthreads();                    // vmcnt drained -> tile 0 ready

    float (*Tw)[36] = T[w];

    for (int t = 0; t < 16; t++) {
        int n1 = cb + t * 64;
        float pb0 = 1024.f - sq[bbase + n1 + l31];
        float pb1 = 1024.f - sq[bbase + n1 + 32 + l31];

        float16v a0 = {};
#pragma unroll
        for (int s = 0; s < 4; s++) {
            int gx = 2 * s + lh;
            int sw = (gx ^ (l31 & 7)) << 4;
            short8v bh0 = *(const short8v*)(pool + l31 * 128 + sw);
            a0 = MFMA32(Ah[s], bh0, a0);    // cols n1+0..31
            a0 = MFMA32(Al[s], bh0, a0);
        }
        sel_phase(a0, Tw, pb0, n1, l31, lh, L);

        float16v a1 = {};
#pragma unroll
        for (int s = 0; s < 4; s++) {
            int gx = 2 * s + lh;
            int sw = (gx ^ (l31 & 7)) << 4;
            short8v bh1 = *(const short8v*)(pool + (32 + l31) * 128 + sw);
            a1 = MFMA32(Ah[s], bh1, a1);    // cols n1+32..63
            a1 = MFMA32(Al[s], bh1, a1);
        }
        __syncthreads();                // all waves done reading pool
        if (t < 15)
            stage_tile(xth + (bbase + n1 + 64) * 64, pool, w, lane);
        sel_phase(a1, Tw, pb1, n1 + 32, l31, lh, L);   // hides load latency
        __syncthreads();                // drains vmcnt -> next tile ready
    }

    // each lane writes its class-16 col list verbatim: [ch*32 + 16*lh, +16)
    {
        u16* cr = cand + (bbase + r0 + 32 * w + l31) * 128 + ch * 32 + 16 * lh;
#pragma unroll
        for (int q = 0; q < 8; q++) {
            u32 pk = (L[2 * q] & 0xFFFu) | ((L[2 * q + 1] & 0xFFFu) << 16);
            *(u32*)(cr + 2 * q) = pk;
        }
    }
}

// ---------------------------------------------------------------------------
// k2b: exact fp32 rescore of 128 candidates/row + distributed bitonic top-20.
// 8192 blocks x 256 thr; wave = one row. Cooperative gather: 4 lanes per
// candidate, each instruction reads 16 full 64B lines. (validated r5)
// ---------------------------------------------------------------------------
__global__ __launch_bounds__(256) void k2b_rescore(const float* __restrict__ xtf,
                                                   const float* __restrict__ sq,
                                                   const u16* __restrict__ cand,
                                                   int* __restrict__ knn) {
    __shared__ float xr[4][64];
    __shared__ u32 cdw[4][64];      // 128 candidate ids (u16 packed)
    __shared__ float dd[4][128];    // raw dot products
    int tid = threadIdx.x;
    int lane = tid & 63, w = tid >> 6;
    int bid = blockIdx.x;
    size_t sb = (size_t)((bid & 7) * 1024 + (bid >> 3));   // batch = XCD slot
    size_t row = sb * 4 + w;
    size_t bbase = (row >> 12) << 12;

    if (lane < 16)
        *(float4*)&xr[w][lane * 4] = *(const float4*)(xtf + row * 64 + lane * 4);
    cdw[w][lane] = ((const u32*)cand)[row * 64 + lane];
    __syncthreads();

    int s = lane & 3, g = lane >> 2;
    const u16* cd16 = (const u16*)&cdw[w][0];

    // lane s covers floats {16q + 4s .. +4) of each candidate row (line q)
    float4 xq[4];
#pragma unroll
    for (int q = 0; q < 4; q++) xq[q] = *(const float4*)&xr[w][16 * q + 4 * s];

    int mm[8];
#pragma unroll
    for (int p = 0; p < 8; p++) mm[p] = cd16[p * 16 + g];

#pragma unroll
    for (int p = 0; p < 8; p++) {
        const float* pm = xtf + (bbase + mm[p]) * 64;
        float d = 0.f;
#pragma unroll
        for (int q = 0; q < 4; q++) {
            float4 v = *(const float4*)(pm + 16 * q + 4 * s);
            d = fmaf(v.x, xq[q].x, d); d = fmaf(v.y, xq[q].y, d);
            d = fmaf(v.z, xq[q].z, d); d = fmaf(v.w, xq[q].w, d);
        }
        d += __shfl_xor(d, 1);
        d += __shfl_xor(d, 2);
        if (s == 0) dd[w][p * 16 + g] = d;
    }

    // exact keys (fp32 score + lowest-index tie-break), 2 per lane
    float dA = dd[w][lane], dB = dd[w][64 + lane];
    int mA = cd16[lane], mB = cd16[64 + lane];
    float sA = fmaf(2.f, dA, -sq[bbase + mA]);
    float sB = fmaf(2.f, dB, -sq[bbase + mB]);
    u64 kA = ((u64)ordf(sA) << 32) | (u32)(~(u32)mA);
    u64 kB = ((u64)ordf(sB) << 32) | (u32)(~(u32)mB);

#pragma unroll
    for (u32 k = 2; k <= 64; k <<= 1) {
#pragma unroll
        for (u32 j2 = k >> 1; j2 >= 1; j2 >>= 1) {
            bool up = ((lane & k) == 0);
            bool lower = ((lane & j2) == 0);
            u64 pA = __shfl_xor(kA, j2);
            u64 mxA = (kA > pA) ? kA : pA, mnA = (kA > pA) ? pA : kA;
            kA = (lower == up) ? mxA : mnA;
            u64 pB = __shfl_xor(kB, j2);
            u64 mxB = (kB > pB) ? kB : pB, mnB = (kB > pB) ? pB : kB;
            kB = (lower == up) ? mxB : mnB;
        }
    }
    u64 rB = __shfl(kB, 63 - lane);
    u64 M = (kA > rB) ? kA : rB;
#pragma unroll
    for (u32 j2 = 32; j2 >= 1; j2 >>= 1) {
        u64 p = __shfl_xor(M, j2);
        bool lower = ((lane & j2) == 0);
        u64 mx = (M > p) ? M : p, mn = (M > p) ? p : M;
        M = lower ? mx : mn;
    }
    if (lane < KSEL)
        knn[row * KSEL + lane] = (int)(~(u32)M);
}

// ---------------------------------------------------------------------------
// k1: y1[n][o] = sum_c x[b][c][n]*Wt[c][o] (o'<64); y2: o'>=64. (validated)
// ---------------------------------------------------------------------------
__global__ __launch_bounds__(256) void k1_prep(const float* __restrict__ x,
                                               const float* __restrict__ Wtg,
                                               float* __restrict__ y1,
                                               float* __restrict__ y2) {
    __shared__ float Xt[64][128];
    __shared__ float Wt[64][128];
    int tid = threadIdx.x;
    int gr0 = blockIdx.x * 128;
    int b = gr0 >> 12;
    int n0 = gr0 & 4095;
    const float* xb = x + (size_t)b * (CDIM * NPTS) + n0;

    for (int k = 0; k < 32; k++) {
        int f = tid + 256 * k;
        int c = f >> 7, j = f & 127;
        Xt[c][j] = xb[(size_t)c * NPTS + j];
        ((float*)Wt)[f] = Wtg[f];
    }
    __syncthreads();

    int tr = tid & 15, tc = tid >> 4;
    float acc[8][8];
#pragma unroll
    for (int i = 0; i < 8; i++)
#pragma unroll
        for (int j = 0; j < 8; j++) acc[i][j] = 0.f;

#pragma unroll 4
    for (int c = 0; c < 64; c++) {
        float a[8], bb[8];
        *(float4*)&a[0]  = *(const float4*)&Xt[c][8 * tr];
        *(float4*)&a[4]  = *(const float4*)&Xt[c][8 * tr + 4];
        *(float4*)&bb[0] = *(const float4*)&Wt[c][8 * tc];
        *(float4*)&bb[4] = *(const float4*)&Wt[c][8 * tc + 4];
#pragma unroll
        for (int i = 0; i < 8; i++)
#pragma unroll
            for (int j = 0; j < 8; j++) acc[i][j] = fmaf(a[i], bb[j], acc[i][j]);
    }

#pragma unroll
    for (int i = 0; i < 8; i++) {
        int r = gr0 + 8 * tr + i;
        float* dst = (tc < 8) ? (y1 + (size_t)r * 64 + 8 * tc)
                              : (y2 + (size_t)r * 64 + (8 * tc - 64));
        float4 s0, s1;
        s0.x = acc[i][0]; s0.y = acc[i][1]; s0.z = acc[i][2]; s0.w = acc[i][3];
        s1.x = acc[i][4]; s1.y = acc[i][5]; s1.z = acc[i][6]; s1.w = acc[i][7];
        *(float4*)dst = s0;
        *(float4*)(dst + 4) = s1;
    }
}

// ---------------------------------------------------------------------------
// k3: out[b][o][n] = max_k y1[b][idx[n][k]][o] + y2[b][n][o] + bias[o]
// XCD-swizzled (batch = bid&7) so y1-gather stays in one XCD's L2.
// ---------------------------------------------------------------------------
__global__ __launch_bounds__(256) void k3_out(const float* __restrict__ y1,
                                              const float* __restrict__ y2,
                                              const int* __restrict__ knn,
                                              const float* __restrict__ bias,
                                              float* __restrict__ out) {
    __shared__ float outT[64][65];
    __shared__ int idxT[64 * KSEL];
    int tid = threadIdx.x;
    int b = blockIdx.x & 7;
    int n0 = ((blockIdx.x >> 3) & 63) * 64;

    for (int f = tid; f < 64 * KSEL; f += 256)
        idxT[f] = knn[((size_t)b * NPTS + n0) * KSEL + f];
    __syncthreads();

    int lane = tid & 63, w = tid >> 6;
    float bl = bias[lane];
    const float* y1b = y1 + (size_t)b * NPTS * 64;

    for (int i = 0; i < 16; i++) {
        int rr = w * 16 + i;
        float acc = -FLT_MAX;
#pragma unroll
        for (int k = 0; k < KSEL; k++) {
            int m = idxT[rr * KSEL + k];
            acc = fmaxf(acc, y1b[(size_t)m * 64 + lane]);
        }
        acc = acc + y2[((size_t)b * NPTS + n0 + rr) * 64 + lane] + bl;
        outT[lane][rr] = acc;
    }
    __syncthreads();

    int j = tid & 63, og = tid >> 6;
    for (int oo = 0; oo < 16; oo++) {
        int o = og * 16 + oo;
        out[((size_t)(b * 64 + o)) * NPTS + n0 + j] = outT[o][j];
    }
}

// ---------------------------------------------------------------------------
extern "C" void kernel_launch(void* const* d_in, const int* in_sizes, int n_in,
                              void* d_out, int out_size, void* d_ws, size_t ws_size,
                              hipStream_t stream) {
    const float* x    = (const float*)d_in[0];   // (8, 64, 4096)
    const float* W    = (const float*)d_in[1];   // (64, 128)
    const float* bias = (const float*)d_in[2];   // (64,)
    float* out = (float*)d_out;                  // (8, 64, 4096)
    float* ws = (float*)d_ws;

    u16* xth   = (u16*)ws;                  // [0,4MB)   dies before k1
    u16* xtl   = (u16*)(ws + OFF_XTL);      // [4,8MB)   dies before k1
    u16* candb = (u16*)(ws + OFF_Y2);       // [8,16MB)  dies before k1 writes y2
    float* y1  = ws + OFF_Y1;
    float* y2  = ws + OFF_Y2;
    float* sq  = ws + OFF_SQ;
    float* Wt  = ws + OFF_WT;
    int* knn   = (int*)(ws + OFF_KNN);
    float* xtf = (float*)d_out;             // fp32 transposed copy; k3 overwrites

    hipLaunchKernelGGL(k0_wt,       dim3(32),   dim3(256), 0, stream, W, Wt);
    hipLaunchKernelGGL(p1_prep,     dim3(512),  dim3(256), 0, stream, x, xtf, xth, xtl, sq);
    hipLaunchKernelGGL(k2_gram,     dim3(1024), dim3(256), 0, stream, xth, xtl, sq, candb);
    hipLaunchKernelGGL(k2b_rescore, dim3(8192), dim3(256), 0, stream, xtf, sq, candb, knn);
    hipLaunchKernelGGL(k1_prep,     dim3(256),  dim3(256), 0, stream, x, Wt, y1, y2);
    hipLaunchKernelGGL(k3_out,      dim3(512),  dim3(256), 0, stream, y1, y2, knn, bias, out);
}

// Round 7
// 186.345 us; speedup vs baseline: 7.3774x; 1.0932x over previous
//
#include <hip/hip_runtime.h>
#include <float.h>

typedef unsigned long long u64;
typedef unsigned int u32;
typedef unsigned short u16;

#define NPTS 4096
#define CDIM 64
#define BATCH 8
#define KSEL 20

// float-unit offsets in ws (~19.6 MB, same footprint as prior rounds)
#define OFF_Y1 0
#define OFF_XTL (BATCH * NPTS * CDIM / 2)       // xth [0,4MB), xtl [4,8MB)
#define OFF_Y2 (BATCH * NPTS * 64)              // [8,16MB): cand during k2/k2b, y2 after
#define OFF_SQ (2 * BATCH * NPTS * 64)
#define OFF_WT (OFF_SQ + BATCH * NPTS)
#define OFF_KNN (OFF_WT + 64 * 128)

typedef __attribute__((ext_vector_type(8))) short short8v;   // 8 bf16 (4 VGPR)
typedef __attribute__((ext_vector_type(16))) float float16v; // MFMA 32x32 acc

#define MFMA32(a, b, c) __builtin_amdgcn_mfma_f32_32x32x16_bf16(a, b, c, 0, 0, 0)

__device__ __forceinline__ u32 ordf(float f) {
    u32 u = __float_as_uint(f);
    return (u >> 31) ? ~u : (u | 0x80000000u);
}
__device__ __forceinline__ u32 umaxu(u32 a, u32 b) { return a > b ? a : b; }
__device__ __forceinline__ u32 uminu(u32 a, u32 b) { return a < b ? a : b; }

__device__ __forceinline__ void load_lds_16(const void* g, void* l) {
    __builtin_amdgcn_global_load_lds(
        (const __attribute__((address_space(1))) unsigned int*)g,
        (__attribute__((address_space(3))) unsigned int*)l, 16, 0, 0);
}

#define CE(i, j) { u32 a_ = c[i], b_ = c[j]; c[i] = umaxu(a_, b_); c[j] = uminu(a_, b_); }

// Batcher odd-even merge sort, 16 u32 keys, descending. 63 CEs (vs 80 bitonic).
__device__ __forceinline__ void sort16_desc(u32 (&c)[16]) {
    CE(0,1) CE(2,3) CE(4,5) CE(6,7) CE(8,9) CE(10,11) CE(12,13) CE(14,15)
    CE(0,2) CE(1,3) CE(4,6) CE(5,7) CE(8,10) CE(9,11) CE(12,14) CE(13,15)
    CE(1,2) CE(5,6) CE(9,10) CE(13,14)
    CE(0,4) CE(1,5) CE(2,6) CE(3,7) CE(8,12) CE(9,13) CE(10,14) CE(11,15)
    CE(2,4) CE(3,5) CE(10,12) CE(11,13)
    CE(1,2) CE(3,4) CE(5,6) CE(9,10) CE(11,12) CE(13,14)
    CE(0,8) CE(1,9) CE(2,10) CE(3,11) CE(4,12) CE(5,13) CE(6,14) CE(7,15)
    CE(4,8) CE(5,9) CE(6,10) CE(7,11)
    CE(2,4) CE(3,5) CE(6,8) CE(7,9) CE(10,12) CE(11,13)
    CE(1,2) CE(3,4) CE(5,6) CE(7,8) CE(9,10) CE(11,12) CE(13,14)
}
#undef CE

// L (desc,16) <- top-16 of L ∪ c (desc,16): max-half + bitonic merge
__device__ __forceinline__ void merge_into16(u32 (&L)[16], const u32 (&c)[16]) {
#pragma unroll
    for (int i = 0; i < 16; i++) L[i] = umaxu(L[i], c[15 - i]);
#pragma unroll
    for (int j = 8; j >= 1; j >>= 1)
#pragma unroll
        for (int i = 0; i < 16; i++)
            if ((i & j) == 0) {
                int p = i | j;
                u32 a = L[i], b = L[p];
                L[i] = umaxu(a, b);
                L[p] = uminu(a, b);
            }
}

// ---------------------------------------------------------------------------
// k0: W (64 x 128) -> Wt[c][o'] (64 x 128): o'<64: W1^T ; o'>=64: (W2-W1)^T
// ---------------------------------------------------------------------------
__global__ void k0_wt(const float* __restrict__ W, float* __restrict__ Wt) {
    int f = blockIdx.x * 256 + threadIdx.x;
    if (f >= 64 * 128) return;
    int c = f >> 7, o = f & 127;
    float v;
    if (o < 64) {
        v = W[o * 128 + c];
    } else {
        int oo = o - 64;
        v = W[oo * 128 + 64 + c] - W[oo * 128 + c];
    }
    Wt[f] = v;
}

// ---------------------------------------------------------------------------
// p1: transpose x[b][c][n] -> xtf (fp32, in d_out), xth/xtl (bf16 hi/lo, RNE),
// sq[n]. (validated rounds 2-6)
// ---------------------------------------------------------------------------
__global__ __launch_bounds__(256) void p1_prep(const float* __restrict__ x,
                                               float* __restrict__ xtf,
                                               u16* __restrict__ xth,
                                               u16* __restrict__ xtl,
                                               float* __restrict__ sq) {
    __shared__ float Xp[64][65];
    int tid = threadIdx.x;
    int b = blockIdx.x >> 6;
    int n0 = (blockIdx.x & 63) * 64;
    const float* xb = x + (size_t)b * (CDIM * NPTS);
    int j = tid & 63, cq = tid >> 6;
#pragma unroll
    for (int i = 0; i < 16; i++) {
        int c = cq * 16 + i;
        Xp[c][j] = xb[(size_t)c * NPTS + n0 + j];
    }
    __syncthreads();
    if (tid < 64) {
        float s = 0.f;
        for (int c = 0; c < 64; c++) { float v = Xp[c][tid]; s = fmaf(v, v, s); }
        sq[(size_t)b * NPTS + n0 + tid] = s;
    }
    int n = tid >> 2, c0 = (tid & 3) * 16;
    float vv[16];
#pragma unroll
    for (int i = 0; i < 16; i++) vv[i] = Xp[c0 + i][n];
    size_t rowb = ((size_t)b * NPTS + n0 + n) * 64 + c0;
#pragma unroll
    for (int q = 0; q < 4; q++) {
        float4 f;
        f.x = vv[4 * q]; f.y = vv[4 * q + 1]; f.z = vv[4 * q + 2]; f.w = vv[4 * q + 3];
        *(float4*)(xtf + rowb + 4 * q) = f;
    }
    u16 hb[16], lb[16];
#pragma unroll
    for (int i = 0; i < 16; i++) {
        float v = vv[i];
        u32 bv = __float_as_uint(v);
        u32 h = (bv + 0x7FFFu + ((bv >> 16) & 1u)) >> 16;    // RNE bf16
        float hf = __uint_as_float(h << 16);
        float lf = v - hf;
        u32 bl = __float_as_uint(lf);
        u32 lo = (bl + 0x7FFFu + ((bl >> 16) & 1u)) >> 16;
        hb[i] = (u16)h; lb[i] = (u16)lo;
    }
    uint4 H0, H1, L0, L1;
    H0.x = hb[0] | ((u32)hb[1] << 16);  H0.y = hb[2] | ((u32)hb[3] << 16);
    H0.z = hb[4] | ((u32)hb[5] << 16);  H0.w = hb[6] | ((u32)hb[7] << 16);
    H1.x = hb[8] | ((u32)hb[9] << 16);  H1.y = hb[10] | ((u32)hb[11] << 16);
    H1.z = hb[12] | ((u32)hb[13] << 16); H1.w = hb[14] | ((u32)hb[15] << 16);
    L0.x = lb[0] | ((u32)lb[1] << 16);  L0.y = lb[2] | ((u32)lb[3] << 16);
    L0.z = lb[4] | ((u32)lb[5] << 16);  L0.w = lb[6] | ((u32)lb[7] << 16);
    L1.x = lb[8] | ((u32)lb[9] << 16);  L1.y = lb[10] | ((u32)lb[11] << 16);
    L1.z = lb[12] | ((u32)lb[13] << 16); L1.w = lb[14] | ((u32)lb[15] << 16);
    *(uint4*)(xth + rowb) = H0;
    *(uint4*)(xth + rowb + 8) = H1;
    *(uint4*)(xtl + rowb) = L0;
    *(uint4*)(xtl + rowb + 8) = L1;
}

// ---------------------------------------------------------------------------
// k2: MFMA Gram (2-product: Ah*Bh + Al*Bh) over (128 rows x 1024-col chunk) +
// per-lane register top-16 per col-class (2 classes = bit4 of col) -> cand.
// Grid 1024 = 8 b x 32 rowtiles x 4 chunks; 256 thr (4 waves); 4 blocks/CU
// (r6's (256,5) caused a 58MB scratch spill: VGPR squeezed to 48 — reverted).
// Single 8 KB B-tile buffer; stage(t+1) issued before sel(a1) so the async
// global_load_lds latency hides under selection VALU work.
// Keys: biased score s+1024 > 0 -> float bits monotone as uint; 20-bit score
// prefix | 12-bit col, bias+2g-sq folded into ONE fmaf at T-write.
// ---------------------------------------------------------------------------
__device__ __forceinline__ void stage_tile(const u16* __restrict__ srcb,
                                           char* lds, int w, int lane) {
#pragma unroll
    for (int i = 0; i < 2; i++) {
        int G = w * 128 + i * 64 + lane;          // 16B granule index in [0,512)
        int rr = G >> 3, gp = G & 7;              // row (gram col), granule-in-row
        const u16* src = srcb + rr * 64 + ((gp ^ (rr & 7)) << 3);
        char* dst = lds + (w * 128 + i * 64) * 16;      // wave-uniform base
        load_lds_16(src, dst);                          // HW adds lane*16
    }
}

// score/select one 32-col acc: write biased scores to Tw, read 16 cols
// (class = lh), mask+tag keys, sort + merge into per-lane top-16.
__device__ __forceinline__ void sel_phase(const float16v& A, float (*Tw)[36],
                                          float pb, int colbase,
                                          int l31, int lh, u32 (&L)[16]) {
#pragma unroll
    for (int r = 0; r < 16; r++) {
        int row = (r & 3) + 8 * (r >> 2) + 4 * lh;   // m101 C/D row map
        Tw[row][l31] = fmaf(2.f, A[r], pb);          // s + 1024, always > 0
    }
    // same-wave LDS RAW: compiler inserts lgkmcnt waits (validated r3-r6)
    u32 c[16];
    const u32* Tu = (const u32*)&Tw[l31][16 * lh];
#pragma unroll
    for (int q = 0; q < 4; q++) {
        uint4 v = *(const uint4*)(Tu + 4 * q);
        u32 cg = (u32)(colbase + 16 * lh + 4 * q);
        c[4 * q + 0] = (v.x & 0xFFFFF000u) | (cg + 0);
        c[4 * q + 1] = (v.y & 0xFFFFF000u) | (cg + 1);
        c[4 * q + 2] = (v.z & 0xFFFFF000u) | (cg + 2);
        c[4 * q + 3] = (v.w & 0xFFFFF000u) | (cg + 3);
    }
    sort16_desc(c);
    merge_into16(L, c);
}

__global__ __launch_bounds__(256, 4) void k2_gram(const u16* __restrict__ xth,
                                                  const u16* __restrict__ xtl,
                                                  const float* __restrict__ sq,
                                                  u16* __restrict__ cand) {
    __shared__ char pool[8192];        // B-tile (hi only, XOR-swizzled)
    __shared__ float T[4][32][36];     // per-wave score transpose (18.4 KB)
    int tid = threadIdx.x;
    int lane = tid & 63, w = tid >> 6;
    int l31 = lane & 31, lh = lane >> 5;
    int b = blockIdx.x & 7;                 // batch == XCD slot -> L2 locality
    int rt = (blockIdx.x >> 3) & 31;
    int ch = blockIdx.x >> 8;
    int r0 = rt * 128;
    int cb = ch * 1024;
    size_t bbase = (size_t)b * NPTS;

    // A fragments: rows r0+32w..+31, K=64 in 4 k-steps (hi+lo, regs all run)
    short8v Ah[4], Al[4];
    {
        const u16* pa = xth + (bbase + r0 + 32 * w + l31) * 64 + 8 * lh;
        const u16* pl = xtl + (bbase + r0 + 32 * w + l31) * 64 + 8 * lh;
#pragma unroll
        for (int s = 0; s < 4; s++) {
            Ah[s] = *(const short8v*)(pa + 16 * s);
            Al[s] = *(const short8v*)(pl + 16 * s);
        }
    }

    u32 L[16];
#pragma unroll
    for (int i = 0; i < 16; i++) L[i] = 0u;

    stage_tile(xth + (bbase + cb) * 64, pool, w, lane);
    __syncthreads();                    // vmcnt drained -> tile 0 ready

    float (*Tw)[36] = T[w];

    for (int t = 0; t < 16; t++) {
        int n1 = cb + t * 64;
        float pb0 = 1024.f - sq[bbase + n1 + l31];
        float pb1 = 1024.f - sq[bbase + n1 + 32 + l31];

        float16v a0 = {};
#pragma unroll
        for (int s = 0; s < 4; s++) {
            int gx = 2 * s + lh;
            int sw = (gx ^ (l31 & 7)) << 4;
            short8v bh0 = *(const short8v*)(pool + l31 * 128 + sw);
            a0 = MFMA32(Ah[s], bh0, a0);    // cols n1+0..31
            a0 = MFMA32(Al[s], bh0, a0);
        }
        sel_phase(a0, Tw, pb0, n1, l31, lh, L);

        float16v a1 = {};
#pragma unroll
        for (int s = 0; s < 4; s++) {
            int gx = 2 * s + lh;
            int sw = (gx ^ (l31 & 7)) << 4;
            short8v bh1 = *(const short8v*)(pool + (32 + l31) * 128 + sw);
            a1 = MFMA32(Ah[s], bh1, a1);    // cols n1+32..63
            a1 = MFMA32(Al[s], bh1, a1);
        }
        __syncthreads();                // all waves done reading pool
        if (t < 15)
            stage_tile(xth + (bbase + n1 + 64) * 64, pool, w, lane);
        sel_phase(a1, Tw, pb1, n1 + 32, l31, lh, L);   // hides load latency
        __syncthreads();                // drains vmcnt -> next tile ready
    }

    // each lane writes its class-16 col list verbatim: [ch*32 + 16*lh, +16)
    {
        u16* cr = cand + (bbase + r0 + 32 * w + l31) * 128 + ch * 32 + 16 * lh;
#pragma unroll
        for (int q = 0; q < 8; q++) {
            u32 pk = (L[2 * q] & 0xFFFu) | ((L[2 * q + 1] & 0xFFFu) << 16);
            *(u32*)(cr + 2 * q) = pk;
        }
    }
}

// ---------------------------------------------------------------------------
// k2b: exact fp32 rescore of 128 candidates/row + distributed bitonic top-20.
// 8192 blocks x 256 thr; wave = one row. Cooperative gather: 4 lanes per
// candidate, each instruction reads 16 full 64B lines. (validated r5/r6)
// ---------------------------------------------------------------------------
__global__ __launch_bounds__(256) void k2b_rescore(const float* __restrict__ xtf,
                                                   const float* __restrict__ sq,
                                                   const u16* __restrict__ cand,
                                                   int* __restrict__ knn) {
    __shared__ float xr[4][64];
    __shared__ u32 cdw[4][64];      // 128 candidate ids (u16 packed)
    __shared__ float dd[4][128];    // raw dot products
    int tid = threadIdx.x;
    int lane = tid & 63, w = tid >> 6;
    int bid = blockIdx.x;
    size_t sb = (size_t)((bid & 7) * 1024 + (bid >> 3));   // batch = XCD slot
    size_t row = sb * 4 + w;
    size_t bbase = (row >> 12) << 12;

    if (lane < 16)
        *(float4*)&xr[w][lane * 4] = *(const float4*)(xtf + row * 64 + lane * 4);
    cdw[w][lane] = ((const u32*)cand)[row * 64 + lane];
    __syncthreads();

    int s = lane & 3, g = lane >> 2;
    const u16* cd16 = (const u16*)&cdw[w][0];

    // lane s covers floats {16q + 4s .. +4) of each candidate row (line q)
    float4 xq[4];
#pragma unroll
    for (int q = 0; q < 4; q++) xq[q] = *(const float4*)&xr[w][16 * q + 4 * s];

    int mm[8];
#pragma unroll
    for (int p = 0; p < 8; p++) mm[p] = cd16[p * 16 + g];

#pragma unroll
    for (int p = 0; p < 8; p++) {
        const float* pm = xtf + (bbase + mm[p]) * 64;
        float d = 0.f;
#pragma unroll
        for (int q = 0; q < 4; q++) {
            float4 v = *(const float4*)(pm + 16 * q + 4 * s);
            d = fmaf(v.x, xq[q].x, d); d = fmaf(v.y, xq[q].y, d);
            d = fmaf(v.z, xq[q].z, d); d = fmaf(v.w, xq[q].w, d);
        }
        d += __shfl_xor(d, 1);
        d += __shfl_xor(d, 2);
        if (s == 0) dd[w][p * 16 + g] = d;
    }

    // exact keys (fp32 score + lowest-index tie-break), 2 per lane
    float dA = dd[w][lane], dB = dd[w][64 + lane];
    int mA = cd16[lane], mB = cd16[64 + lane];
    float sA = fmaf(2.f, dA, -sq[bbase + mA]);
    float sB = fmaf(2.f, dB, -sq[bbase + mB]);
    u64 kA = ((u64)ordf(sA) << 32) | (u32)(~(u32)mA);
    u64 kB = ((u64)ordf(sB) << 32) | (u32)(~(u32)mB);

#pragma unroll
    for (u32 k = 2; k <= 64; k <<= 1) {
#pragma unroll
        for (u32 j2 = k >> 1; j2 >= 1; j2 >>= 1) {
            bool up = ((lane & k) == 0);
            bool lower = ((lane & j2) == 0);
            u64 pA = __shfl_xor(kA, j2);
            u64 mxA = (kA > pA) ? kA : pA, mnA = (kA > pA) ? pA : kA;
            kA = (lower == up) ? mxA : mnA;
            u64 pB = __shfl_xor(kB, j2);
            u64 mxB = (kB > pB) ? kB : pB, mnB = (kB > pB) ? pB : kB;
            kB = (lower == up) ? mxB : mnB;
        }
    }
    u64 rB = __shfl(kB, 63 - lane);
    u64 M = (kA > rB) ? kA : rB;
#pragma unroll
    for (u32 j2 = 32; j2 >= 1; j2 >>= 1) {
        u64 p = __shfl_xor(M, j2);
        bool lower = ((lane & j2) == 0);
        u64 mx = (M > p) ? M : p, mn = (M > p) ? p : M;
        M = lower ? mx : mn;
    }
    if (lane < KSEL)
        knn[row * KSEL + lane] = (int)(~(u32)M);
}

// ---------------------------------------------------------------------------
// k1: y1[n][o] = sum_c x[b][c][n]*Wt[c][o] (o'<64); y2: o'>=64. (validated)
// ---------------------------------------------------------------------------
__global__ __launch_bounds__(256) void k1_prep(const float* __restrict__ x,
                                               const float* __restrict__ Wtg,
                                               float* __restrict__ y1,
                                               float* __restrict__ y2) {
    __shared__ float Xt[64][128];
    __shared__ float Wt[64][128];
    int tid = threadIdx.x;
    int gr0 = blockIdx.x * 128;
    int b = gr0 >> 12;
    int n0 = gr0 & 4095;
    const float* xb = x + (size_t)b * (CDIM * NPTS) + n0;

    for (int k = 0; k < 32; k++) {
        int f = tid + 256 * k;
        int c = f >> 7, j = f & 127;
        Xt[c][j] = xb[(size_t)c * NPTS + j];
        ((float*)Wt)[f] = Wtg[f];
    }
    __syncthreads();

    int tr = tid & 15, tc = tid >> 4;
    float acc[8][8];
#pragma unroll
    for (int i = 0; i < 8; i++)
#pragma unroll
        for (int j = 0; j < 8; j++) acc[i][j] = 0.f;

#pragma unroll 4
    for (int c = 0; c < 64; c++) {
        float a[8], bb[8];
        *(float4*)&a[0]  = *(const float4*)&Xt[c][8 * tr];
        *(float4*)&a[4]  = *(const float4*)&Xt[c][8 * tr + 4];
        *(float4*)&bb[0] = *(const float4*)&Wt[c][8 * tc];
        *(float4*)&bb[4] = *(const float4*)&Wt[c][8 * tc + 4];
#pragma unroll
        for (int i = 0; i < 8; i++)
#pragma unroll
            for (int j = 0; j < 8; j++) acc[i][j] = fmaf(a[i], bb[j], acc[i][j]);
    }

#pragma unroll
    for (int i = 0; i < 8; i++) {
        int r = gr0 + 8 * tr + i;
        float* dst = (tc < 8) ? (y1 + (size_t)r * 64 + 8 * tc)
                              : (y2 + (size_t)r * 64 + (8 * tc - 64));
        float4 s0, s1;
        s0.x = acc[i][0]; s0.y = acc[i][1]; s0.z = acc[i][2]; s0.w = acc[i][3];
        s1.x = acc[i][4]; s1.y = acc[i][5]; s1.z = acc[i][6]; s1.w = acc[i][7];
        *(float4*)dst = s0;
        *(float4*)(dst + 4) = s1;
    }
}

// ---------------------------------------------------------------------------
// k3: out[b][o][n] = max_k y1[b][idx[n][k]][o] + y2[b][n][o] + bias[o]
// XCD-swizzled (batch = bid&7) so y1-gather stays in one XCD's L2.
// ---------------------------------------------------------------------------
__global__ __launch_bounds__(256) void k3_out(const float* __restrict__ y1,
                                              const float* __restrict__ y2,
                                              const int* __restrict__ knn,
                                              const float* __restrict__ bias,
                                              float* __restrict__ out) {
    __shared__ float outT[64][65];
    __shared__ int idxT[64 * KSEL];
    int tid = threadIdx.x;
    int b = blockIdx.x & 7;
    int n0 = ((blockIdx.x >> 3) & 63) * 64;

    for (int f = tid; f < 64 * KSEL; f += 256)
        idxT[f] = knn[((size_t)b * NPTS + n0) * KSEL + f];
    __syncthreads();

    int lane = tid & 63, w = tid >> 6;
    float bl = bias[lane];
    const float* y1b = y1 + (size_t)b * NPTS * 64;

    for (int i = 0; i < 16; i++) {
        int rr = w * 16 + i;
        float acc = -FLT_MAX;
#pragma unroll
        for (int k = 0; k < KSEL; k++) {
            int m = idxT[rr * KSEL + k];
            acc = fmaxf(acc, y1b[(size_t)m * 64 + lane]);
        }
        acc = acc + y2[((size_t)b * NPTS + n0 + rr) * 64 + lane] + bl;
        outT[lane][rr] = acc;
    }
    __syncthreads();

    int j = tid & 63, og = tid >> 6;
    for (int oo = 0; oo < 16; oo++) {
        int o = og * 16 + oo;
        out[((size_t)(b * 64 + o)) * NPTS + n0 + j] = outT[o][j];
    }
}

// ---------------------------------------------------------------------------
extern "C" void kernel_launch(void* const* d_in, const int* in_sizes, int n_in,
                              void* d_out, int out_size, void* d_ws, size_t ws_size,
                              hipStream_t stream) {
    const float* x    = (const float*)d_in[0];   // (8, 64, 4096)
    const float* W    = (const float*)d_in[1];   // (64, 128)
    const float* bias = (const float*)d_in[2];   // (64,)
    float* out = (float*)d_out;                  // (8, 64, 4096)
    float* ws = (float*)d_ws;

    u16* xth   = (u16*)ws;                  // [0,4MB)   dies before k1
    u16* xtl   = (u16*)(ws + OFF_XTL);      // [4,8MB)   dies before k1
    u16* candb = (u16*)(ws + OFF_Y2);       // [8,16MB)  dies before k1 writes y2
    float* y1  = ws + OFF_Y1;
    float* y2  = ws + OFF_Y2;
    float* sq  = ws + OFF_SQ;
    float* Wt  = ws + OFF_WT;
    int* knn   = (int*)(ws + OFF_KNN);
    float* xtf = (float*)d_out;             // fp32 transposed copy; k3 overwrites

    hipLaunchKernelGGL(k0_wt,       dim3(32),   dim3(256), 0, stream, W, Wt);
    hipLaunchKernelGGL(p1_prep,     dim3(512),  dim3(256), 0, stream, x, xtf, xth, xtl, sq);
    hipLaunchKernelGGL(k2_gram,     dim3(1024), dim3(256), 0, stream, xth, xtl, sq, candb);
    hipLaunchKernelGGL(k2b_rescore, dim3(8192), dim3(256), 0, stream, xtf, sq, candb, knn);
    hipLaunchKernelGGL(k1_prep,     dim3(256),  dim3(256), 0, stream, x, Wt, y1, y2);
    hipLaunchKernelGGL(k3_out,      dim3(512),  dim3(256), 0, stream, y1, y2, knn, bias, out);
}

// Round 8
// 166.917 us; speedup vs baseline: 8.2360x; 1.1164x over previous
//
#include <hip/hip_runtime.h>
#include <float.h>

typedef unsigned long long u64;
typedef unsigned int u32;
typedef unsigned short u16;

#define NPTS 4096
#define CDIM 64
#define BATCH 8
#define KSEL 20

// float-unit offsets in ws (~19.6 MB, same footprint as prior rounds)
#define OFF_Y1 0
#define OFF_XTL (BATCH * NPTS * CDIM / 2)       // xth [0,4MB), xtl [4,8MB)
#define OFF_Y2 (BATCH * NPTS * 64)              // [8,16MB): cand keys during k2/k2b, y2 after
#define OFF_SQ (2 * BATCH * NPTS * 64)
#define OFF_WT (OFF_SQ + BATCH * NPTS)
#define OFF_KNN (OFF_WT + 64 * 128)

typedef __attribute__((ext_vector_type(8))) short short8v;   // 8 bf16 (4 VGPR)
typedef __attribute__((ext_vector_type(16))) float float16v; // MFMA 32x32 acc

#define MFMA32(a, b, c) __builtin_amdgcn_mfma_f32_32x32x16_bf16(a, b, c, 0, 0, 0)

__device__ __forceinline__ u32 ordf(float f) {
    u32 u = __float_as_uint(f);
    return (u >> 31) ? ~u : (u | 0x80000000u);
}
__device__ __forceinline__ u32 umaxu(u32 a, u32 b) { return a > b ? a : b; }
__device__ __forceinline__ u32 uminu(u32 a, u32 b) { return a < b ? a : b; }

__device__ __forceinline__ void load_lds_16(const void* g, void* l) {
    __builtin_amdgcn_global_load_lds(
        (const __attribute__((address_space(1))) unsigned int*)g,
        (__attribute__((address_space(3))) unsigned int*)l, 16, 0, 0);
}

#define CE(i, j) { u32 a_ = c[i], b_ = c[j]; c[i] = umaxu(a_, b_); c[j] = uminu(a_, b_); }

// Batcher odd-even merge sort, 16 u32 keys, descending. 63 CEs.
__device__ __forceinline__ void sort16_desc(u32 (&c)[16]) {
    CE(0,1) CE(2,3) CE(4,5) CE(6,7) CE(8,9) CE(10,11) CE(12,13) CE(14,15)
    CE(0,2) CE(1,3) CE(4,6) CE(5,7) CE(8,10) CE(9,11) CE(12,14) CE(13,15)
    CE(1,2) CE(5,6) CE(9,10) CE(13,14)
    CE(0,4) CE(1,5) CE(2,6) CE(3,7) CE(8,12) CE(9,13) CE(10,14) CE(11,15)
    CE(2,4) CE(3,5) CE(10,12) CE(11,13)
    CE(1,2) CE(3,4) CE(5,6) CE(9,10) CE(11,12) CE(13,14)
    CE(0,8) CE(1,9) CE(2,10) CE(3,11) CE(4,12) CE(5,13) CE(6,14) CE(7,15)
    CE(4,8) CE(5,9) CE(6,10) CE(7,11)
    CE(2,4) CE(3,5) CE(6,8) CE(7,9) CE(10,12) CE(11,13)
    CE(1,2) CE(3,4) CE(5,6) CE(7,8) CE(9,10) CE(11,12) CE(13,14)
}
#undef CE

// L (desc,16) <- top-16 of L ∪ c (desc,16): max-half + bitonic merge
__device__ __forceinline__ void merge_into16(u32 (&L)[16], const u32 (&c)[16]) {
#pragma unroll
    for (int i = 0; i < 16; i++) L[i] = umaxu(L[i], c[15 - i]);
#pragma unroll
    for (int j = 8; j >= 1; j >>= 1)
#pragma unroll
        for (int i = 0; i < 16; i++)
            if ((i & j) == 0) {
                int p = i | j;
                u32 a = L[i], b = L[p];
                L[i] = umaxu(a, b);
                L[p] = uminu(a, b);
            }
}

// ---------------------------------------------------------------------------
// k0: W (64 x 128) -> Wt[c][o'] (64 x 128): o'<64: W1^T ; o'>=64: (W2-W1)^T
// ---------------------------------------------------------------------------
__global__ void k0_wt(const float* __restrict__ W, float* __restrict__ Wt) {
    int f = blockIdx.x * 256 + threadIdx.x;
    if (f >= 64 * 128) return;
    int c = f >> 7, o = f & 127;
    float v;
    if (o < 64) {
        v = W[o * 128 + c];
    } else {
        int oo = o - 64;
        v = W[oo * 128 + 64 + c] - W[oo * 128 + c];
    }
    Wt[f] = v;
}

// ---------------------------------------------------------------------------
// p1: transpose x[b][c][n] -> xtf (fp32, in d_out), xth/xtl (bf16 hi/lo, RNE),
// sq[n]. (validated rounds 2-7)
// ---------------------------------------------------------------------------
__global__ __launch_bounds__(256) void p1_prep(const float* __restrict__ x,
                                               float* __restrict__ xtf,
                                               u16* __restrict__ xth,
                                               u16* __restrict__ xtl,
                                               float* __restrict__ sq) {
    __shared__ float Xp[64][65];
    int tid = threadIdx.x;
    int b = blockIdx.x >> 6;
    int n0 = (blockIdx.x & 63) * 64;
    const float* xb = x + (size_t)b * (CDIM * NPTS);
    int j = tid & 63, cq = tid >> 6;
#pragma unroll
    for (int i = 0; i < 16; i++) {
        int c = cq * 16 + i;
        Xp[c][j] = xb[(size_t)c * NPTS + n0 + j];
    }
    __syncthreads();
    if (tid < 64) {
        float s = 0.f;
        for (int c = 0; c < 64; c++) { float v = Xp[c][tid]; s = fmaf(v, v, s); }
        sq[(size_t)b * NPTS + n0 + tid] = s;
    }
    int n = tid >> 2, c0 = (tid & 3) * 16;
    float vv[16];
#pragma unroll
    for (int i = 0; i < 16; i++) vv[i] = Xp[c0 + i][n];
    size_t rowb = ((size_t)b * NPTS + n0 + n) * 64 + c0;
#pragma unroll
    for (int q = 0; q < 4; q++) {
        float4 f;
        f.x = vv[4 * q]; f.y = vv[4 * q + 1]; f.z = vv[4 * q + 2]; f.w = vv[4 * q + 3];
        *(float4*)(xtf + rowb + 4 * q) = f;
    }
    u16 hb[16], lb[16];
#pragma unroll
    for (int i = 0; i < 16; i++) {
        float v = vv[i];
        u32 bv = __float_as_uint(v);
        u32 h = (bv + 0x7FFFu + ((bv >> 16) & 1u)) >> 16;    // RNE bf16
        float hf = __uint_as_float(h << 16);
        float lf = v - hf;
        u32 bl = __float_as_uint(lf);
        u32 lo = (bl + 0x7FFFu + ((bl >> 16) & 1u)) >> 16;
        hb[i] = (u16)h; lb[i] = (u16)lo;
    }
    uint4 H0, H1, L0, L1;
    H0.x = hb[0] | ((u32)hb[1] << 16);  H0.y = hb[2] | ((u32)hb[3] << 16);
    H0.z = hb[4] | ((u32)hb[5] << 16);  H0.w = hb[6] | ((u32)hb[7] << 16);
    H1.x = hb[8] | ((u32)hb[9] << 16);  H1.y = hb[10] | ((u32)hb[11] << 16);
    H1.z = hb[12] | ((u32)hb[13] << 16); H1.w = hb[14] | ((u32)hb[15] << 16);
    L0.x = lb[0] | ((u32)lb[1] << 16);  L0.y = lb[2] | ((u32)lb[3] << 16);
    L0.z = lb[4] | ((u32)lb[5] << 16);  L0.w = lb[6] | ((u32)lb[7] << 16);
    L1.x = lb[8] | ((u32)lb[9] << 16);  L1.y = lb[10] | ((u32)lb[11] << 16);
    L1.z = lb[12] | ((u32)lb[13] << 16); L1.w = lb[14] | ((u32)lb[15] << 16);
    *(uint4*)(xth + rowb) = H0;
    *(uint4*)(xth + rowb + 8) = H1;
    *(uint4*)(xtl + rowb) = L0;
    *(uint4*)(xtl + rowb + 8) = L1;
}

// ---------------------------------------------------------------------------
// k2: MFMA Gram (2-product: Ah*Bh + Al*Bh) over (128 rows x 1024-col chunk) +
// per-lane register top-16 per col-class; epilogue merges the two classes and
// stores the row's chunk-top-16 as FULL u32 keys (score prefix | 12-bit col).
// Grid 1024 = 8 b x 32 rowtiles x 4 chunks; 256 thr (4 waves); 4 blocks/CU.
// ---------------------------------------------------------------------------
__device__ __forceinline__ void stage_tile(const u16* __restrict__ srcb,
                                           char* lds, int w, int lane) {
#pragma unroll
    for (int i = 0; i < 2; i++) {
        int G = w * 128 + i * 64 + lane;          // 16B granule index in [0,512)
        int rr = G >> 3, gp = G & 7;              // row (gram col), granule-in-row
        const u16* src = srcb + rr * 64 + ((gp ^ (rr & 7)) << 3);
        char* dst = lds + (w * 128 + i * 64) * 16;      // wave-uniform base
        load_lds_16(src, dst);                          // HW adds lane*16
    }
}

// score/select one 32-col acc: write biased scores to Tw, read 16 cols
// (class = lh), mask+tag keys, sort + merge into per-lane top-16.
__device__ __forceinline__ void sel_phase(const float16v& A, float (*Tw)[36],
                                          float pb, int colbase,
                                          int l31, int lh, u32 (&L)[16]) {
#pragma unroll
    for (int r = 0; r < 16; r++) {
        int row = (r & 3) + 8 * (r >> 2) + 4 * lh;   // m101 C/D row map
        Tw[row][l31] = fmaf(2.f, A[r], pb);          // s + 1024, always > 0
    }
    // same-wave LDS RAW: compiler inserts lgkmcnt waits (validated r3-r7)
    u32 c[16];
    const u32* Tu = (const u32*)&Tw[l31][16 * lh];
#pragma unroll
    for (int q = 0; q < 4; q++) {
        uint4 v = *(const uint4*)(Tu + 4 * q);
        u32 cg = (u32)(colbase + 16 * lh + 4 * q);
        c[4 * q + 0] = (v.x & 0xFFFFF000u) | (cg + 0);
        c[4 * q + 1] = (v.y & 0xFFFFF000u) | (cg + 1);
        c[4 * q + 2] = (v.z & 0xFFFFF000u) | (cg + 2);
        c[4 * q + 3] = (v.w & 0xFFFFF000u) | (cg + 3);
    }
    sort16_desc(c);
    merge_into16(L, c);
}

__global__ __launch_bounds__(256, 4) void k2_gram(const u16* __restrict__ xth,
                                                  const u16* __restrict__ xtl,
                                                  const float* __restrict__ sq,
                                                  u32* __restrict__ cand) {
    __shared__ char pool[8192];        // B-tile (hi only, XOR-swizzled)
    __shared__ float T[4][32][36];     // per-wave score transpose (18.4 KB)
    int tid = threadIdx.x;
    int lane = tid & 63, w = tid >> 6;
    int l31 = lane & 31, lh = lane >> 5;
    int b = blockIdx.x & 7;                 // batch == XCD slot -> L2 locality
    int rt = (blockIdx.x >> 3) & 31;
    int ch = blockIdx.x >> 8;
    int r0 = rt * 128;
    int cb = ch * 1024;
    size_t bbase = (size_t)b * NPTS;

    // A fragments: rows r0+32w..+31, K=64 in 4 k-steps (hi+lo, regs all run)
    short8v Ah[4], Al[4];
    {
        const u16* pa = xth + (bbase + r0 + 32 * w + l31) * 64 + 8 * lh;
        const u16* pl = xtl + (bbase + r0 + 32 * w + l31) * 64 + 8 * lh;
#pragma unroll
        for (int s = 0; s < 4; s++) {
            Ah[s] = *(const short8v*)(pa + 16 * s);
            Al[s] = *(const short8v*)(pl + 16 * s);
        }
    }

    u32 L[16];
#pragma unroll
    for (int i = 0; i < 16; i++) L[i] = 0u;

    stage_tile(xth + (bbase + cb) * 64, pool, w, lane);
    __syncthreads();                    // vmcnt drained -> tile 0 ready

    float (*Tw)[36] = T[w];

    for (int t = 0; t < 16; t++) {
        int n1 = cb + t * 64;
        float pb0 = 1024.f - sq[bbase + n1 + l31];
        float pb1 = 1024.f - sq[bbase + n1 + 32 + l31];

        float16v a0 = {};
#pragma unroll
        for (int s = 0; s < 4; s++) {
            int gx = 2 * s + lh;
            int sw = (gx ^ (l31 & 7)) << 4;
            short8v bh0 = *(const short8v*)(pool + l31 * 128 + sw);
            a0 = MFMA32(Ah[s], bh0, a0);    // cols n1+0..31
            a0 = MFMA32(Al[s], bh0, a0);
        }
        sel_phase(a0, Tw, pb0, n1, l31, lh, L);

        float16v a1 = {};
#pragma unroll
        for (int s = 0; s < 4; s++) {
            int gx = 2 * s + lh;
            int sw = (gx ^ (l31 & 7)) << 4;
            short8v bh1 = *(const short8v*)(pool + (32 + l31) * 128 + sw);
            a1 = MFMA32(Ah[s], bh1, a1);    // cols n1+32..63
            a1 = MFMA32(Al[s], bh1, a1);
        }
        __syncthreads();                // all waves done reading pool
        if (t < 15)
            stage_tile(xth + (bbase + n1 + 64) * 64, pool, w, lane);
        sel_phase(a1, Tw, pb1, n1 + 32, l31, lh, L);   // hides load latency
        __syncthreads();                // drains vmcnt -> next tile ready
    }

    // merge the row's two class-lists: top-16 of union = max(A_i, B_{15-i}),
    // then bitonic-merge-16 (r2-validated pattern). Store full u32 keys.
    u32 M[16];
#pragma unroll
    for (int i = 0; i < 16; i++) {
        u32 pv = __shfl_xor(L[15 - i], 32);
        M[i] = umaxu(L[i], pv);
    }
#pragma unroll
    for (int j = 8; j >= 1; j >>= 1)
#pragma unroll
        for (int i = 0; i < 16; i++)
            if ((i & j) == 0) {
                int p = i | j;
                u32 a = M[i], b2 = M[p];
                M[i] = umaxu(a, b2);
                M[p] = uminu(a, b2);
            }
    if (lane < 32) {
        u32* cr = cand + (bbase + r0 + 32 * w + l31) * 64 + ch * 16;
#pragma unroll
        for (int q = 0; q < 4; q++) {
            uint4 v;
            v.x = M[4 * q]; v.y = M[4 * q + 1]; v.z = M[4 * q + 2]; v.w = M[4 * q + 3];
            *(uint4*)(cr + 4 * q) = v;
        }
    }
}

// ---------------------------------------------------------------------------
// k2b: per row, sort the 64 quantized keys (4 chunks x 16) with a 64-lane
// bitonic sort, exact-fp32-rescore only the top-32, then top-20 by u64 key.
// 8192 blocks x 256 thr; wave = one row. Gather: 4 lanes/candidate (16 full
// 64B lines per instruction, r7-validated), 2 passes of 16 candidates.
// ---------------------------------------------------------------------------
__global__ __launch_bounds__(256) void k2b_rescore(const float* __restrict__ xtf,
                                                   const float* __restrict__ sq,
                                                   const u32* __restrict__ cand,
                                                   int* __restrict__ knn) {
    __shared__ float xr[4][64];
    __shared__ float dd[4][32];
    __shared__ u32 cols[4][32];
    int tid = threadIdx.x;
    int lane = tid & 63, w = tid >> 6;
    int bid = blockIdx.x;
    size_t sb = (size_t)((bid & 7) * 1024 + (bid >> 3));   // batch = XCD slot
    size_t row = sb * 4 + w;
    size_t bbase = (row >> 12) << 12;

    if (lane < 16)
        *(float4*)&xr[w][lane * 4] = *(const float4*)(xtf + row * 64 + lane * 4);
    u32 key = cand[row * 64 + lane];

    // bitonic sort-64 desc on quantized keys (one per lane)
#pragma unroll
    for (u32 k = 2; k <= 64; k <<= 1) {
#pragma unroll
        for (u32 j2 = k >> 1; j2 >= 1; j2 >>= 1) {
            bool up = ((lane & k) == 0);
            bool lower = ((lane & j2) == 0);
            u32 p = __shfl_xor(key, j2);
            u32 mx = (key > p) ? key : p, mn = (key > p) ? p : key;
            key = (lower == up) ? mx : mn;
        }
    }
    if (lane < 32) cols[w][lane] = key & 0xFFFu;   // top-32 candidates' cols

    // cooperative exact rescore: 2 passes x 16 candidates, 4 lanes each
    int s = lane & 3, g = lane >> 2;
    float4 xq[4];
#pragma unroll
    for (int q = 0; q < 4; q++) xq[q] = *(const float4*)&xr[w][16 * q + 4 * s];

#pragma unroll
    for (int p = 0; p < 2; p++) {
        int m = cols[w][p * 16 + g];
        const float* pm = xtf + (bbase + m) * 64;
        float d = 0.f;
#pragma unroll
        for (int q = 0; q < 4; q++) {
            float4 v = *(const float4*)(pm + 16 * q + 4 * s);
            d = fmaf(v.x, xq[q].x, d); d = fmaf(v.y, xq[q].y, d);
            d = fmaf(v.z, xq[q].z, d); d = fmaf(v.w, xq[q].w, d);
        }
        d += __shfl_xor(d, 1);
        d += __shfl_xor(d, 2);
        if (s == 0) dd[w][p * 16 + g] = d;
    }

    // exact u64 keys (fp32 score + lowest-index tie-break), lanes 0..31
    u64 kE = 0;
    if (lane < 32) {
        int m = (int)cols[w][lane];
        float sE = fmaf(2.f, dd[w][lane], -sq[bbase + m]);
        kE = ((u64)ordf(sE) << 32) | (u32)(~(u32)m);
    }
    // bitonic sort-64 desc (lanes >=32 hold 0 sentinels, below any real key)
#pragma unroll
    for (u32 k = 2; k <= 64; k <<= 1) {
#pragma unroll
        for (u32 j2 = k >> 1; j2 >= 1; j2 >>= 1) {
            bool up = ((lane & k) == 0);
            bool lower = ((lane & j2) == 0);
            u64 p = __shfl_xor(kE, j2);
            u64 mx = (kE > p) ? kE : p, mn = (kE > p) ? p : kE;
            kE = (lower == up) ? mx : mn;
        }
    }
    if (lane < KSEL)
        knn[row * KSEL + lane] = (int)(~(u32)kE);
}

// ---------------------------------------------------------------------------
// k1: y1[n][o] = sum_c x[b][c][n]*Wt[c][o] (o'<64); y2: o'>=64. (validated)
// ---------------------------------------------------------------------------
__global__ __launch_bounds__(256) void k1_prep(const float* __restrict__ x,
                                               const float* __restrict__ Wtg,
                                               float* __restrict__ y1,
                                               float* __restrict__ y2) {
    __shared__ float Xt[64][128];
    __shared__ float Wt[64][128];
    int tid = threadIdx.x;
    int gr0 = blockIdx.x * 128;
    int b = gr0 >> 12;
    int n0 = gr0 & 4095;
    const float* xb = x + (size_t)b * (CDIM * NPTS) + n0;

    for (int k = 0; k < 32; k++) {
        int f = tid + 256 * k;
        int c = f >> 7, j = f & 127;
        Xt[c][j] = xb[(size_t)c * NPTS + j];
        ((float*)Wt)[f] = Wtg[f];
    }
    __syncthreads();

    int tr = tid & 15, tc = tid >> 4;
    float acc[8][8];
#pragma unroll
    for (int i = 0; i < 8; i++)
#pragma unroll
        for (int j = 0; j < 8; j++) acc[i][j] = 0.f;

#pragma unroll 4
    for (int c = 0; c < 64; c++) {
        float a[8], bb[8];
        *(float4*)&a[0]  = *(const float4*)&Xt[c][8 * tr];
        *(float4*)&a[4]  = *(const float4*)&Xt[c][8 * tr + 4];
        *(float4*)&bb[0] = *(const float4*)&Wt[c][8 * tc];
        *(float4*)&bb[4] = *(const float4*)&Wt[c][8 * tc + 4];
#pragma unroll
        for (int i = 0; i < 8; i++)
#pragma unroll
            for (int j = 0; j < 8; j++) acc[i][j] = fmaf(a[i], bb[j], acc[i][j]);
    }

#pragma unroll
    for (int i = 0; i < 8; i++) {
        int r = gr0 + 8 * tr + i;
        float* dst = (tc < 8) ? (y1 + (size_t)r * 64 + 8 * tc)
                              : (y2 + (size_t)r * 64 + (8 * tc - 64));
        float4 s0, s1;
        s0.x = acc[i][0]; s0.y = acc[i][1]; s0.z = acc[i][2]; s0.w = acc[i][3];
        s1.x = acc[i][4]; s1.y = acc[i][5]; s1.z = acc[i][6]; s1.w = acc[i][7];
        *(float4*)dst = s0;
        *(float4*)(dst + 4) = s1;
    }
}

// ---------------------------------------------------------------------------
// k3: out[b][o][n] = max_k y1[b][idx[n][k]][o] + y2[b][n][o] + bias[o]
// 1024 blocks (b x 128 tiles of 32 rows) for 4 blocks/CU latency hiding.
// ---------------------------------------------------------------------------
__global__ __launch_bounds__(256) void k3_out(const float* __restrict__ y1,
                                              const float* __restrict__ y2,
                                              const int* __restrict__ knn,
                                              const float* __restrict__ bias,
                                              float* __restrict__ out) {
    __shared__ float outT[64][33];   // [o][n-local], +1 pad
    __shared__ int idxT[32 * KSEL];
    int tid = threadIdx.x;
    int b = blockIdx.x & 7;
    int n0 = (blockIdx.x >> 3) * 32;

    for (int f = tid; f < 32 * KSEL; f += 256)
        idxT[f] = knn[((size_t)b * NPTS + n0) * KSEL + f];
    __syncthreads();

    int lane = tid & 63, w = tid >> 6;
    float bl = bias[lane];
    const float* y1b = y1 + (size_t)b * NPTS * 64;

    for (int i = 0; i < 8; i++) {
        int rr = w * 8 + i;
        float acc = -FLT_MAX;
#pragma unroll
        for (int k = 0; k < KSEL; k++) {
            int m = idxT[rr * KSEL + k];
            acc = fmaxf(acc, y1b[(size_t)m * 64 + lane]);
        }
        acc = acc + y2[((size_t)b * NPTS + n0 + rr) * 64 + lane] + bl;
        outT[lane][rr] = acc;
    }
    __syncthreads();

    int j = tid & 31, og = tid >> 5;
    for (int it = 0; it < 8; it++) {
        int o = it * 8 + og;
        out[((size_t)(b * 64 + o)) * NPTS + n0 + j] = outT[o][j];
    }
}

// ---------------------------------------------------------------------------
extern "C" void kernel_launch(void* const* d_in, const int* in_sizes, int n_in,
                              void* d_out, int out_size, void* d_ws, size_t ws_size,
                              hipStream_t stream) {
    const float* x    = (const float*)d_in[0];   // (8, 64, 4096)
    const float* W    = (const float*)d_in[1];   // (64, 128)
    const float* bias = (const float*)d_in[2];   // (64,)
    float* out = (float*)d_out;                  // (8, 64, 4096)
    float* ws = (float*)d_ws;

    u16* xth   = (u16*)ws;                  // [0,4MB)   dies before k1
    u16* xtl   = (u16*)(ws + OFF_XTL);      // [4,8MB)   dies before k1
    u32* candb = (u32*)(ws + OFF_Y2);       // [8,16MB)  keys; dies before k1 writes y2
    float* y1  = ws + OFF_Y1;
    float* y2  = ws + OFF_Y2;
    float* sq  = ws + OFF_SQ;
    float* Wt  = ws + OFF_WT;
    int* knn   = (int*)(ws + OFF_KNN);
    float* xtf = (float*)d_out;             // fp32 transposed copy; k3 overwrites

    hipLaunchKernelGGL(k0_wt,       dim3(32),   dim3(256), 0, stream, W, Wt);
    hipLaunchKernelGGL(p1_prep,     dim3(512),  dim3(256), 0, stream, x, xtf, xth, xtl, sq);
    hipLaunchKernelGGL(k2_gram,     dim3(1024), dim3(256), 0, stream, xth, xtl, sq, candb);
    hipLaunchKernelGGL(k2b_rescore, dim3(8192), dim3(256), 0, stream, xtf, sq, candb, knn);
    hipLaunchKernelGGL(k1_prep,     dim3(256),  dim3(256), 0, stream, x, Wt, y1, y2);
    hipLaunchKernelGGL(k3_out,      dim3(1024), dim3(256), 0, stream, y1, y2, knn, bias, out);
}